// Round 6
// baseline (14013.788 us; speedup 1.0000x reference)
//
#include <hip/hip_runtime.h>
#include <stdint.h>

#define TSEQ 1024
#define H 256
#define H3 768
#define NV 50000
#define NBLK 256
#define NTHR 512
#define RPB 196            // 256 * 196 = 50176 >= 50000
#define SOS_TOK 2
#define SPIN_LIM 262144

// ---- workspace layout (bytes) ----
#define WS_SALT   0                          // u32, bumped by k_init every launch
#define WS_PART   4096                       // u64[2 slots][256 blocks][8 words] = 32 KB
#define WS_GIENC  65536                      // float[1024*768] = 3MB
#define WS_TABLE  (65536 + TSEQ * H3 * 4)
#define TABLE_BYTES ((size_t)NV * H3 * 4)

using u64 = unsigned long long;

// relaxed agent-scope atomics: straight to LLC, no wbl2/inv fences, no ordering needed
__device__ __forceinline__ void awr(u64* p, u64 v) {
  __hip_atomic_store(p, v, __ATOMIC_RELAXED, __HIP_MEMORY_SCOPE_AGENT);
}
__device__ __forceinline__ u64 ard(u64* p) {
  return __hip_atomic_load(p, __ATOMIC_RELAXED, __HIP_MEMORY_SCOPE_AGENT);
}
__device__ __forceinline__ u64 pkf(unsigned tg, float f) {
  return ((u64)tg << 32) | (u64)__float_as_uint(f);
}
__device__ __forceinline__ u64 pki(unsigned tg, int v) {
  return ((u64)tg << 32) | (u64)(unsigned)v;
}
__device__ __forceinline__ float upf(u64 w) { return __uint_as_float((unsigned)w); }
__device__ __forceinline__ unsigned tagof(u64 w) { return (unsigned)(w >> 32); }

// pin a float4 into VGPRs: "+v" makes the value opaque -> no remat/reload from global
#define PIN4(v) asm volatile("" : "+v"((v).x), "+v"((v).y), "+v"((v).z), "+v"((v).w))

// ---- init: bump per-launch salt (graph-replay safe) ----
extern "C" __global__ void k_init(char* ws) {
  if (threadIdx.x == 0) {
    unsigned* s = (unsigned*)(ws + WS_SALT);
    *s = *s + 1u;
  }
}

// ---- encoder input-transform: gi_enc[t][r] = b_ih[r] + w_ih[r,:] @ enc_emb[x[t]], 16 tokens/block ----
extern "C" __global__ void k_enc_gi(const int* __restrict__ x, const float* __restrict__ emb,
                                    const float* __restrict__ wih, const float* __restrict__ bih,
                                    float* __restrict__ gi) {
  int tid = threadIdx.x;
  int t0 = blockIdx.x * 16;
  __shared__ float4 se4[16][H / 4];
  float* se = (float*)se4;
  for (int idx = tid; idx < 16 * H; idx += 256) {
    int j = idx >> 8, k = idx & 255;
    se[j * H + k] = emb[(size_t)x[t0 + j] * H + k];
  }
  __syncthreads();
  for (int q = 0; q < 3; q++) {
    int r = q * H + tid;
    const float4* w4 = (const float4*)(wih + (size_t)r * H);
    float bb = bih[r];
    float a[16];
#pragma unroll
    for (int j = 0; j < 16; j++) a[j] = bb;
    for (int k = 0; k < H / 4; k++) {
      float4 wv = w4[k];
#pragma unroll
      for (int j = 0; j < 16; j++) {
        float4 ev = se4[j][k];
        a[j] += wv.x * ev.x + wv.y * ev.y + wv.z * ev.z + wv.w * ev.w;
      }
    }
#pragma unroll
    for (int j = 0; j < 16; j++) gi[(size_t)(t0 + j) * H3 + r] = a[j];
  }
}

// ---- decoder gi table: table[v][r] = b_ih[r] + w_ih[r,:] @ relu(dec_emb[v]) ----
extern "C" __global__ void k_table(const float* __restrict__ emb, const float* __restrict__ wih,
                                   const float* __restrict__ bih, float* __restrict__ table) {
  int tid = threadIdx.x;
  int v0 = blockIdx.x * 16;
  __shared__ float4 se4[16][H / 4];
  float* se = (float*)se4;
  for (int idx = tid; idx < 16 * H; idx += 256) {
    int j = idx >> 8, k = idx & 255;
    se[j * H + k] = fmaxf(emb[(size_t)(v0 + j) * H + k], 0.f);
  }
  __syncthreads();
  for (int q = 0; q < 3; q++) {
    int r = q * H + tid;
    const float4* w4 = (const float4*)(wih + (size_t)r * H);
    float bb = bih[r];
    float a[16];
#pragma unroll
    for (int j = 0; j < 16; j++) a[j] = bb;
    for (int k = 0; k < H / 4; k++) {
      float4 wv = w4[k];
#pragma unroll
      for (int j = 0; j < 16; j++) {
        float4 ev = se4[j][k];
        a[j] += wv.x * ev.x + wv.y * ev.y + wv.z * ev.z + wv.w * ev.w;
      }
    }
#pragma unroll
    for (int j = 0; j < 16; j++) table[(size_t)(v0 + j) * H3 + r] = a[j];
  }
}

// ---- persistent symmetric kernel: per-lane spin-until-tag exchange ----
extern "C" __global__ void __launch_bounds__(NTHR, 1)
k_main(const float* __restrict__ enc_whh, const float* __restrict__ enc_bhh,
       const float* __restrict__ dec_emb, const float* __restrict__ dec_wih,
       const float* __restrict__ dec_whh, const float* __restrict__ dec_bih,
       const float* __restrict__ dec_bhh, const float* __restrict__ w_out,
       const float* __restrict__ b_out, float* __restrict__ out,
       char* __restrict__ ws, int use_table) {
  const int b = blockIdx.x, tid = threadIdx.x;
  u64* part = (u64*)(ws + WS_PART);                 // [2][256][8] u64, 64B/record
  const float* gi_enc = (const float*)(ws + WS_GIENC);
  const float* table = (const float*)(ws + WS_TABLE);

  __shared__ float sh_h[H];
  __shared__ float sh_we[3][H];      // encoder rows {b, H+b, 2H+b}
  __shared__ float sh_wd[3][H];      // decoder rows {3b, 3b+1, 3b+2}
  __shared__ float sh_wi[3][H];
  __shared__ float sh_gi[H3];
  __shared__ float gh_lds[H3];
  __shared__ float sh_logit[RPB];
  __shared__ float sh_bout[RPB];
  __shared__ float sh_gh3[3];
  __shared__ float sh_rv[8];
  __shared__ float sh_mv[8];
  __shared__ int sh_mi[8];
  __shared__ float sh_sv[8];
  __shared__ float sh_mv2[8];
  __shared__ int sh_mi2[8];
  __shared__ float sh_sv2[8];
  __shared__ float sh_e[H];
  __shared__ int sh_abort;

  if (tid == 0) sh_abort = 0;

  // ---- prologue staging ----
  for (int k = tid; k < 3 * H; k += NTHR) {
    int q = k >> 8, c = k & 255;
    sh_we[q][c] = enc_whh[((size_t)(q * H + b)) * H + c];
    sh_wd[q][c] = dec_whh[((size_t)(3 * b + q)) * H + c];
    if (!use_table) sh_wi[q][c] = dec_wih[((size_t)(3 * b + q)) * H + c];
  }
  const float be0 = enc_bhh[b], be1 = enc_bhh[H + b], be2 = enc_bhh[2 * H + b];
  const float bd0 = dec_bhh[3 * b], bd1 = dec_bhh[3 * b + 1], bd2 = dec_bhh[3 * b + 2];
  float bi0 = 0.f, bi1 = 0.f, bi2 = 0.f;
  if (!use_table) { bi0 = dec_bih[3 * b]; bi1 = dec_bih[3 * b + 1]; bi2 = dec_bih[3 * b + 2]; }
  const int rowbase = b * RPB;
  const int nrows = min(RPB, max(0, NV - rowbase));
  const int p = tid >> 1, hf = tid & 1;
  const bool wact = (p < nrows);
  float4 wreg[32];
  if (wact) {
    const float4* wp = (const float4*)(w_out + (size_t)(rowbase + p) * H + hf * 128);
#pragma unroll
    for (int i = 0; i < 32; ++i) wreg[i] = wp[i];
  } else {
#pragma unroll
    for (int i = 0; i < 32; ++i) wreg[i] = make_float4(0.f, 0.f, 0.f, 0.f);
  }
#pragma unroll
  for (int i = 0; i < 32; ++i) PIN4(wreg[i]);      // force VGPR residency
  if (tid < RPB) sh_bout[tid] = (tid < nrows) ? b_out[rowbase + tid] : 0.f;
  const unsigned tagbase = (*(volatile unsigned*)(ws + WS_SALT)) * 65536u;
  __syncthreads();

  auto wave_maxidx = [&](float& mv, int& mi) {
#pragma unroll
    for (int off = 32; off >= 1; off >>= 1) {
      float ov = __shfl_xor(mv, off);
      int oi = __shfl_xor(mi, off);
      if (ov > mv || (ov == mv && oi < mi)) { mv = ov; mi = oi; }
    }
  };
  // 3 rows of (wr @ vin) + bias triple -> sh_gh3[0..2]
  auto row3 = [&](const float(&wr)[3][H], float bb0, float bb1, float bb2, const float* vin) {
    int q = tid >> 7, i = tid & 127;
    float pp = 0.f;
    if (q < 3) pp = wr[q][2 * i] * vin[2 * i] + wr[q][2 * i + 1] * vin[2 * i + 1];
#pragma unroll
    for (int off = 32; off >= 1; off >>= 1) pp += __shfl_xor(pp, off);
    if (q < 3 && (tid & 63) == 0) sh_rv[tid >> 6] = pp;
    __syncthreads();
    if (tid == 0) {
      sh_gh3[0] = sh_rv[0] + sh_rv[1] + bb0;
      sh_gh3[1] = sh_rv[2] + sh_rv[3] + bb1;
      sh_gh3[2] = sh_rv[4] + sh_rv[5] + bb2;
    }
    __syncthreads();
  };
  auto gru_step = [&]() {
    if (tid < H) {
      float gir = sh_gi[tid], giz = sh_gi[H + tid], gin = sh_gi[2 * H + tid];
      float ghr = gh_lds[tid], ghz = gh_lds[H + tid], ghn = gh_lds[2 * H + tid];
      float r = 1.f / (1.f + expf(-(gir + ghr)));
      float z = 1.f / (1.f + expf(-(giz + ghz)));
      float n = tanhf(gin + r * ghn);
      sh_h[tid] = (1.f - z) * n + z * sh_h[tid];
    }
    __syncthreads();
  };
  // per-lane spin-until-tag gathers (no per-sweep barrier, no fences)
  auto spin1 = [&](unsigned tg, float* dst) {
    if (tid < NBLK) {
      u64* pp = part + (size_t)(tg & 1) * 2048 + (size_t)tid * 8;
      u64 w = 0; int n = 0;
      do { w = ard(pp); } while (tagof(w) != tg && ++n < SPIN_LIM);
      if (tagof(w) != tg) sh_abort = 1;
      dst[tid] = upf(w);
    }
    __syncthreads();
  };
  auto spin3 = [&](unsigned tg, float* dst) {
    if (tid < NBLK) {
      u64* pp = part + (size_t)(tg & 1) * 2048 + (size_t)tid * 8;
      u64 w2 = 0, w3 = 0, w4 = 0; int n = 0; bool ok;
      do {
        w2 = ard(pp + 2); w3 = ard(pp + 3); w4 = ard(pp + 4);
        ok = (tagof(w2) == tg) & (tagof(w3) == tg) & (tagof(w4) == tg);
      } while (!ok && ++n < SPIN_LIM);
      if (!ok) sh_abort = 1;
      dst[3 * tid] = upf(w2); dst[3 * tid + 1] = upf(w3); dst[3 * tid + 2] = upf(w4);
    }
    __syncthreads();
  };
  auto spin6 = [&](unsigned tg, float& bmx, int& bix, float& bsm) {
    if (tid < NBLK) {
      u64* pp = part + (size_t)(tg & 1) * 2048 + (size_t)tid * 8;
      u64 w0 = 0, w1 = 0, w2 = 0, w3 = 0, w4 = 0, w5 = 0; int n = 0; bool ok;
      do {
        w0 = ard(pp + 0); w1 = ard(pp + 1); w2 = ard(pp + 2);
        w3 = ard(pp + 3); w4 = ard(pp + 4); w5 = ard(pp + 5);
        ok = (tagof(w0) == tg) & (tagof(w1) == tg) & (tagof(w2) == tg) &
             (tagof(w3) == tg) & (tagof(w4) == tg) & (tagof(w5) == tg);
      } while (!ok && ++n < SPIN_LIM);
      if (!ok) sh_abort = 1;
      gh_lds[3 * tid] = upf(w2); gh_lds[3 * tid + 1] = upf(w3); gh_lds[3 * tid + 2] = upf(w4);
      bmx = upf(w0); bix = (int)(unsigned)w1; bsm = upf(w5);
    }
    __syncthreads();
  };
  auto pub1 = [&](unsigned tg, float v) {   // caller guards tid==0
    u64* d = part + (size_t)(tg & 1) * 2048 + (size_t)b * 8;
    awr(d + 0, pkf(tg, v));
  };
  auto pub3v = [&](unsigned tg) {           // sh_gh3 -> words 2..4; caller guards tid==0
    u64* d = part + (size_t)(tg & 1) * 2048 + (size_t)b * 8;
    awr(d + 2, pkf(tg, sh_gh3[0]));
    awr(d + 3, pkf(tg, sh_gh3[1]));
    awr(d + 4, pkf(tg, sh_gh3[2]));
  };
  auto pub6 = [&](unsigned tg, float bmax, float bsum, int bidx) {
    if (tid == 0) {
      u64* d = part + (size_t)(tg & 1) * 2048 + (size_t)b * 8;
      awr(d + 0, pkf(tg, bmax));
      awr(d + 1, pki(tg, bidx));
      awr(d + 2, pkf(tg, sh_gh3[0]));
      awr(d + 3, pkf(tg, sh_gh3[1]));
      awr(d + 4, pkf(tg, sh_gh3[2]));
      awr(d + 5, pkf(tg, bsum));
    }
  };

  int e = 0;
  // ===================== ENCODER (distributed h: block b owns h[b]) =====================
  float hb;
  {
    // h_1[b] from gi_enc[0] and gh(h_0=0)=bias (uniform across threads)
    float g0 = gi_enc[b], g1 = gi_enc[H + b], g2 = gi_enc[2 * H + b];
    float r = 1.f / (1.f + expf(-(g0 + be0)));
    float z = 1.f / (1.f + expf(-(g1 + be1)));
    float n = tanhf(g2 + r * be2);
    hb = (1.f - z) * n;
    e = 1;
    if (tid == 0) pub1(tagbase + 1u, hb);
  }
  for (int t = 1; t < TSEQ; ++t) {
    // issue gi scalars early (uniform loads), then gather h_t
    float g0 = gi_enc[(size_t)t * H3 + b];
    float g1 = gi_enc[(size_t)t * H3 + H + b];
    float g2 = gi_enc[(size_t)t * H3 + 2 * H + b];
    spin1(tagbase + (unsigned)t, sh_h);
    if (sh_abort) return;
    row3(sh_we, be0, be1, be2, sh_h);   // rows {b, H+b, 2H+b} of W_hh @ h_t
    float r = 1.f / (1.f + expf(-(g0 + sh_gh3[0])));
    float z = 1.f / (1.f + expf(-(g1 + sh_gh3[1])));
    float n = tanhf(g2 + r * sh_gh3[2]);
    hb = (1.f - z) * n + z * hb;        // h_{t+1}[b]
    ++e;
    if (tid == 0) pub1(tagbase + (unsigned)e, hb);
  }
  // final gather: h_enc
  spin1(tagbase + (unsigned)e, sh_h);
  if (sh_abort) return;

  // ===================== BRIDGE: exchange dec-gh(h_enc) =====================
  row3(sh_wd, bd0, bd1, bd2, sh_h);
  ++e;
  if (tid == 0) pub3v(tagbase + (unsigned)e);
  spin3(tagbase + (unsigned)e, gh_lds);
  if (sh_abort) return;

  // ===================== DECODER (full-h redundant, one exchange/step) =====================
  int tok = SOS_TOK;
  for (int t = 0; t < TSEQ; ++t) {
    if (use_table) {
      if (tid < 384) {
        float2 gp = *(const float2*)(table + (size_t)tok * H3 + 2 * tid);
        sh_gi[2 * tid] = gp.x; sh_gi[2 * tid + 1] = gp.y;
      }
      __syncthreads();
    } else {
      for (int j = tid; j < H; j += NTHR) sh_e[j] = fmaxf(dec_emb[(size_t)tok * H + j], 0.f);
      __syncthreads();
      row3(sh_wi, bi0, bi1, bi2, sh_e);
      ++e;
      if (tid == 0) pub3v(tagbase + (unsigned)e);
      spin3(tagbase + (unsigned)e, sh_gi);
      if (sh_abort) return;
    }
    gru_step();                        // h_t (bitwise-identical in all blocks)
    // logits from register-resident w_out
#pragma unroll
    for (int i = 0; i < 32; ++i) PIN4(wreg[i]);   // keep resident across the loop
    float acc = 0.f;
    if (wact) {
      const float4* h4 = ((const float4*)sh_h) + hf * 32;
#pragma unroll
      for (int i = 0; i < 32; ++i) {
        float4 wv = wreg[i], hv = h4[i];
        acc += wv.x * hv.x + wv.y * hv.y + wv.z * hv.z + wv.w * hv.w;
      }
    }
    acc += __shfl_xor(acc, 1);
    if (wact && hf == 0) sh_logit[p] = acc + sh_bout[p];
    __syncthreads();
    // block-local max/argmax
    float mv = (tid < nrows) ? sh_logit[tid] : -INFINITY;
    int mi = (tid < nrows) ? (rowbase + tid) : 0x7fffffff;
    wave_maxidx(mv, mi);
    if ((tid & 63) == 0) { sh_mv[tid >> 6] = mv; sh_mi[tid >> 6] = mi; }
    __syncthreads();
    float bmax = sh_mv[0]; int bidx = sh_mi[0];
#pragma unroll
    for (int k = 1; k < 8; ++k)
      if (sh_mv[k] > bmax || (sh_mv[k] == bmax && sh_mi[k] < bidx)) { bmax = sh_mv[k]; bidx = sh_mi[k]; }
    // block-local sum of exp (output-only path)
    float ec = (tid < nrows) ? __expf(sh_logit[tid] - bmax) : 0.f;
#pragma unroll
    for (int off = 32; off >= 1; off >>= 1) ec += __shfl_xor(ec, off);
    if ((tid & 63) == 0) sh_sv[tid >> 6] = ec;
    __syncthreads();
    float bsum = 0.f;
#pragma unroll
    for (int k = 0; k < 8; ++k) bsum += sh_sv[k];
    // gh rows for t+1
    row3(sh_wd, bd0, bd1, bd2, sh_h);
    // one exchange: {bmax, idx, gh0..2, bsum}
    ++e;
    unsigned tg = tagbase + (unsigned)e;
    pub6(tg, bmax, bsum, bidx);
    float bm_e = -INFINITY, sv = 0.f; int ie = 0x7fffffff;
    spin6(tg, bm_e, ie, sv);
    if (sh_abort) return;
    if (tid >= NBLK) { bm_e = -INFINITY; sv = 0.f; ie = 0x7fffffff; }
    // merge argmax FIRST -> tok
    float mv2 = bm_e; int mi2 = ie;
    wave_maxidx(mv2, mi2);
    if ((tid & 63) == 0) { sh_mv2[tid >> 6] = mv2; sh_mi2[tid >> 6] = mi2; }
    __syncthreads();
    float gmax = sh_mv2[0]; int gidx = sh_mi2[0];
#pragma unroll
    for (int k = 1; k < 8; ++k)
      if (sh_mv2[k] > gmax || (sh_mv2[k] == gmax && sh_mi2[k] < gidx)) { gmax = sh_mv2[k]; gidx = sh_mi2[k]; }
    tok = gidx;
    // lse merge + output row
    float c = (tid < NBLK) ? sv * __expf(bm_e - gmax) : 0.f;
#pragma unroll
    for (int off = 32; off >= 1; off >>= 1) c += __shfl_xor(c, off);
    if ((tid & 63) == 0) sh_sv2[tid >> 6] = c;
    __syncthreads();
    float S = 0.f;
#pragma unroll
    for (int k = 0; k < 8; ++k) S += sh_sv2[k];
    float lse = gmax + logf(S);
    if (tid < nrows) out[(size_t)t * NV + rowbase + tid] = sh_logit[tid] - lse;
  }
}

extern "C" void kernel_launch(void* const* d_in, const int* in_sizes, int n_in,
                              void* d_out, int out_size, void* d_ws, size_t ws_size,
                              hipStream_t stream) {
  (void)in_sizes; (void)n_in; (void)out_size;
  const int* x = (const int*)d_in[0];
  const float* enc_emb = (const float*)d_in[1];
  const float* enc_wih = (const float*)d_in[2];
  const float* enc_whh = (const float*)d_in[3];
  const float* enc_bih = (const float*)d_in[4];
  const float* enc_bhh = (const float*)d_in[5];
  const float* dec_emb = (const float*)d_in[6];
  const float* dec_wih = (const float*)d_in[7];
  const float* dec_whh = (const float*)d_in[8];
  const float* dec_bih = (const float*)d_in[9];
  const float* dec_bhh = (const float*)d_in[10];
  const float* w_out = (const float*)d_in[11];
  const float* b_out = (const float*)d_in[12];
  float* out = (float*)d_out;
  char* ws = (char*)d_ws;

  int use_table = (ws_size >= (size_t)WS_TABLE + TABLE_BYTES) ? 1 : 0;

  k_init<<<1, 64, 0, stream>>>(ws);
  k_enc_gi<<<TSEQ / 16, 256, 0, stream>>>(x, enc_emb, enc_wih, enc_bih, (float*)(ws + WS_GIENC));
  if (use_table)
    k_table<<<NV / 16, 256, 0, stream>>>(dec_emb, dec_wih, dec_bih, (float*)(ws + WS_TABLE));
  k_main<<<NBLK, NTHR, 0, stream>>>(enc_whh, enc_bhh, dec_emb, dec_wih, dec_whh, dec_bih,
                                    dec_bhh, w_out, b_out, out, ws, use_table);
}

// Round 7
// 13165.811 us; speedup vs baseline: 1.0644x; 1.0644x over previous
//
#include <hip/hip_runtime.h>
#include <stdint.h>

#define TSEQ 1024
#define H 256
#define H3 768
#define NV 50000
#define NBLK 256
#define NTHR 512
#define RPB 196            // 256 * 196 = 50176 >= 50000
#define SOS_TOK 2
#define SPIN_LIM (1 << 20)

// ---- workspace layout (bytes) ----
#define WS_SALT   0                          // u32, bumped by k_init every launch
#define WS_HENC   1024                       // u64[2][256] packed (encoder h words)   4KB
#define WS_PMX    8192                       // u64[2][256] packed (decoder gate word) 4KB
#define WS_REC    16384                      // u64[2][256][4] (gh0,gh1,gh2,bsum)     16KB
#define WS_GIENC  65536                      // float[1024*768] = 3MB
#define WS_TABLE  (65536 + TSEQ * H3 * 4)
#define TABLE_BYTES ((size_t)NV * H3 * 4)

using u64 = unsigned long long;

// relaxed agent-scope atomics: straight to LLC, no wbl2/inv fences, no ordering needed
__device__ __forceinline__ void awr(u64* p, u64 v) {
  __hip_atomic_store(p, v, __ATOMIC_RELAXED, __HIP_MEMORY_SCOPE_AGENT);
}
__device__ __forceinline__ u64 ard(u64* p) {
  return __hip_atomic_load(p, __ATOMIC_RELAXED, __HIP_MEMORY_SCOPE_AGENT);
}
__device__ __forceinline__ u64 pkf(unsigned tg, float f) {
  return ((u64)tg << 32) | (u64)__float_as_uint(f);
}
__device__ __forceinline__ float upf(u64 w) { return __uint_as_float((unsigned)w); }
__device__ __forceinline__ unsigned tagof(u64 w) { return (unsigned)(w >> 32); }

// explicit AGPR residency for the w_out fragment (compiler cannot remat through these)
__device__ __forceinline__ void agpr_w(float& dst, float v) {
  asm volatile("v_accvgpr_write_b32 %0, %1" : "=a"(dst) : "v"(v));
}
__device__ __forceinline__ float agpr_r(float src) {
  float v;
  asm volatile("v_accvgpr_read_b32 %0, %1" : "=v"(v) : "a"(src));
  return v;
}

// ---- init: bump per-launch salt (graph-replay safe; tags self-invalidate) ----
extern "C" __global__ void k_init(char* ws) {
  if (threadIdx.x == 0) {
    unsigned* s = (unsigned*)(ws + WS_SALT);
    *s = *s + 1u;
  }
}

// ---- encoder input-transform: gi_enc[t][r] = b_ih[r] + w_ih[r,:] @ enc_emb[x[t]] ----
extern "C" __global__ void k_enc_gi(const int* __restrict__ x, const float* __restrict__ emb,
                                    const float* __restrict__ wih, const float* __restrict__ bih,
                                    float* __restrict__ gi) {
  int tid = threadIdx.x;
  int t0 = blockIdx.x * 16;
  __shared__ float4 se4[16][H / 4];
  float* se = (float*)se4;
  for (int idx = tid; idx < 16 * H; idx += 256) {
    int j = idx >> 8, k = idx & 255;
    se[j * H + k] = emb[(size_t)x[t0 + j] * H + k];
  }
  __syncthreads();
  for (int q = 0; q < 3; q++) {
    int r = q * H + tid;
    const float4* w4 = (const float4*)(wih + (size_t)r * H);
    float bb = bih[r];
    float a[16];
#pragma unroll
    for (int j = 0; j < 16; j++) a[j] = bb;
    for (int k = 0; k < H / 4; k++) {
      float4 wv = w4[k];
#pragma unroll
      for (int j = 0; j < 16; j++) {
        float4 ev = se4[j][k];
        a[j] += wv.x * ev.x + wv.y * ev.y + wv.z * ev.z + wv.w * ev.w;
      }
    }
#pragma unroll
    for (int j = 0; j < 16; j++) gi[(size_t)(t0 + j) * H3 + r] = a[j];
  }
}

// ---- decoder gi table: table[v][r] = b_ih[r] + w_ih[r,:] @ relu(dec_emb[v]) ----
extern "C" __global__ void k_table(const float* __restrict__ emb, const float* __restrict__ wih,
                                   const float* __restrict__ bih, float* __restrict__ table) {
  int tid = threadIdx.x;
  int v0 = blockIdx.x * 16;
  __shared__ float4 se4[16][H / 4];
  float* se = (float*)se4;
  for (int idx = tid; idx < 16 * H; idx += 256) {
    int j = idx >> 8, k = idx & 255;
    se[j * H + k] = fmaxf(emb[(size_t)(v0 + j) * H + k], 0.f);
  }
  __syncthreads();
  for (int q = 0; q < 3; q++) {
    int r = q * H + tid;
    const float4* w4 = (const float4*)(wih + (size_t)r * H);
    float bb = bih[r];
    float a[16];
#pragma unroll
    for (int j = 0; j < 16; j++) a[j] = bb;
    for (int k = 0; k < H / 4; k++) {
      float4 wv = w4[k];
#pragma unroll
      for (int j = 0; j < 16; j++) {
        float4 ev = se4[j][k];
        a[j] += wv.x * ev.x + wv.y * ev.y + wv.z * ev.z + wv.w * ev.w;
      }
    }
#pragma unroll
    for (int j = 0; j < 16; j++) table[(size_t)(v0 + j) * H3 + r] = a[j];
  }
}

// ---- persistent symmetric kernel ----
extern "C" __global__ void __launch_bounds__(NTHR, 1)
k_main(const float* __restrict__ enc_whh, const float* __restrict__ enc_bhh,
       const float* __restrict__ dec_emb, const float* __restrict__ dec_wih,
       const float* __restrict__ dec_whh, const float* __restrict__ dec_bih,
       const float* __restrict__ dec_bhh, const float* __restrict__ w_out,
       const float* __restrict__ b_out, float* __restrict__ out,
       char* __restrict__ ws, int use_table) {
  const int b = blockIdx.x, tid = threadIdx.x;
  u64* henc = (u64*)(ws + WS_HENC);      // [2][256] packed
  u64* pmx = (u64*)(ws + WS_PMX);        // [2][256] packed gate words
  u64* rec = (u64*)(ws + WS_REC);        // [2][256][4]
  const float* gi_enc = (const float*)(ws + WS_GIENC);
  const float* table = (const float*)(ws + WS_TABLE);

  __shared__ float sh_h[H];
  __shared__ float sh_we[3][H];      // encoder W_hh rows {b, H+b, 2H+b}
  __shared__ float sh_wd[3][H];      // decoder W_hh rows {3b, 3b+1, 3b+2}
  __shared__ float sh_wi[3][H];
  __shared__ float sh_gi[H3];
  __shared__ float gh_lds[H3];
  __shared__ float sh_logit[RPB];
  __shared__ float sh_bout[RPB];
  __shared__ float sh_gh3[3];
  __shared__ float sh_rv[8];
  __shared__ float sh_mv[8];
  __shared__ int sh_mi[8];
  __shared__ float sh_sv[8];
  __shared__ float sh_mv2[8];
  __shared__ int sh_mi2[8];
  __shared__ float sh_sv2[8];
  __shared__ float sh_e[H];
  __shared__ int sh_abort;

  if (tid == 0) sh_abort = 0;

  // ---- prologue staging ----
  for (int k = tid; k < 3 * H; k += NTHR) {
    int q = k >> 8, c = k & 255;
    sh_we[q][c] = enc_whh[((size_t)(q * H + b)) * H + c];
    sh_wd[q][c] = dec_whh[((size_t)(3 * b + q)) * H + c];
    if (!use_table) sh_wi[q][c] = dec_wih[((size_t)(3 * b + q)) * H + c];
  }
  const float be0 = enc_bhh[b], be1 = enc_bhh[H + b], be2 = enc_bhh[2 * H + b];
  const float bd0 = dec_bhh[3 * b], bd1 = dec_bhh[3 * b + 1], bd2 = dec_bhh[3 * b + 2];
  float bi0 = 0.f, bi1 = 0.f, bi2 = 0.f;
  if (!use_table) { bi0 = dec_bih[3 * b]; bi1 = dec_bih[3 * b + 1]; bi2 = dec_bih[3 * b + 2]; }
  const int rowbase = b * RPB;
  const int nrows = min(RPB, max(0, NV - rowbase));
  const int p = tid >> 1, hf = tid & 1;
  const bool wact = (p < nrows);
  // w_out fragment -> 128 AGPRs per thread (guaranteed on-chip)
  float wa[128];
  {
    const float4* wp = (const float4*)(w_out + (size_t)(rowbase + (wact ? p : 0)) * H + hf * 128);
#pragma unroll
    for (int i = 0; i < 32; ++i) {
      float4 v = wact ? wp[i] : make_float4(0.f, 0.f, 0.f, 0.f);
      agpr_w(wa[4 * i + 0], v.x);
      agpr_w(wa[4 * i + 1], v.y);
      agpr_w(wa[4 * i + 2], v.z);
      agpr_w(wa[4 * i + 3], v.w);
    }
  }
  if (tid < RPB) sh_bout[tid] = (tid < nrows) ? b_out[rowbase + tid] : 0.f;
  const unsigned salt = *(volatile unsigned*)(ws + WS_SALT);
  const unsigned tb32 = salt * 65536u;           // 32-bit tags (henc, rec)
  const unsigned tb16 = salt * 4096u;            // 16-bit tags (pmx), e < 4096
  __syncthreads();

  auto wave_maxidx = [&](float& mv, int& mi) {
#pragma unroll
    for (int off = 32; off >= 1; off >>= 1) {
      float ov = __shfl_xor(mv, off);
      int oi = __shfl_xor(mi, off);
      if (ov > mv || (ov == mv && oi < mi)) { mv = ov; mi = oi; }
    }
  };
  auto row3 = [&](const float(&wr)[3][H], float bb0, float bb1, float bb2, const float* vin) {
    int q = tid >> 7, i = tid & 127;
    float pp = 0.f;
    if (q < 3) pp = wr[q][2 * i] * vin[2 * i] + wr[q][2 * i + 1] * vin[2 * i + 1];
#pragma unroll
    for (int off = 32; off >= 1; off >>= 1) pp += __shfl_xor(pp, off);
    if (q < 3 && (tid & 63) == 0) sh_rv[tid >> 6] = pp;
    __syncthreads();
    if (tid == 0) {
      sh_gh3[0] = sh_rv[0] + sh_rv[1] + bb0;
      sh_gh3[1] = sh_rv[2] + sh_rv[3] + bb1;
      sh_gh3[2] = sh_rv[4] + sh_rv[5] + bb2;
    }
    __syncthreads();
  };
  auto gru_step = [&]() {
    if (tid < H) {
      float gir = sh_gi[tid], giz = sh_gi[H + tid], gin = sh_gi[2 * H + tid];
      float ghr = gh_lds[tid], ghz = gh_lds[H + tid], ghn = gh_lds[2 * H + tid];
      float r = 1.f / (1.f + expf(-(gir + ghr)));
      float z = 1.f / (1.f + expf(-(giz + ghz)));
      float n = tanhf(gin + r * ghn);
      sh_h[tid] = (1.f - z) * n + z * sh_h[tid];
    }
    __syncthreads();
  };
  // per-lane spin on packed word array (32 cache lines)
  auto spin_pk = [&](u64* arr, unsigned tg32) -> u64 {
    u64 w = 0;
    if (tid < NBLK) {
      int n = 0;
      do { w = ard(arr + tid); } while (tagof(w) != tg32 && ++n < SPIN_LIM);
      if (tagof(w) != tg32) sh_abort = 1;
    }
    __syncthreads();
    return w;
  };
  // validated 3-word gather from rec (gi fallback / bridge)
  auto spin_rec3 = [&](unsigned tg, float* dst) {
    if (tid < NBLK) {
      u64* pp_ = rec + (size_t)(tg & 1) * 1024 + (size_t)tid * 4;
      u64 w0 = 0, w1 = 0, w2 = 0; int n = 0; bool ok;
      do {
        w0 = ard(pp_ + 0); w1 = ard(pp_ + 1); w2 = ard(pp_ + 2);
        ok = (tagof(w0) == tg) & (tagof(w1) == tg) & (tagof(w2) == tg);
      } while (!ok && ++n < SPIN_LIM);
      if (!ok) sh_abort = 1;
      dst[3 * tid] = upf(w0); dst[3 * tid + 1] = upf(w1); dst[3 * tid + 2] = upf(w2);
    }
    __syncthreads();
  };

  int e = 0;
  // ===================== ENCODER (distributed h: block b owns h[b]) =====================
  float hb;
  {
    float g0 = gi_enc[b], g1 = gi_enc[H + b], g2 = gi_enc[2 * H + b];
    float r = 1.f / (1.f + expf(-(g0 + be0)));
    float z = 1.f / (1.f + expf(-(g1 + be1)));
    float n = tanhf(g2 + r * be2);
    hb = (1.f - z) * n;
    e = 1;
    if (tid == 0) awr(henc + (e & 1) * 256 + b, pkf(tb32 + 1u, hb));
  }
  for (int t = 1; t < TSEQ; ++t) {
    float g0 = gi_enc[(size_t)t * H3 + b];
    float g1 = gi_enc[(size_t)t * H3 + H + b];
    float g2 = gi_enc[(size_t)t * H3 + 2 * H + b];
    u64 w = spin_pk(henc + (e & 1) * 256, tb32 + (unsigned)e);
    if (sh_abort) return;
    if (tid < NBLK) sh_h[tid] = upf(w);
    __syncthreads();
    row3(sh_we, be0, be1, be2, sh_h);
    float r = 1.f / (1.f + expf(-(g0 + sh_gh3[0])));
    float z = 1.f / (1.f + expf(-(g1 + sh_gh3[1])));
    float n = tanhf(g2 + r * sh_gh3[2]);
    hb = (1.f - z) * n + z * hb;
    ++e;
    if (tid == 0) awr(henc + (e & 1) * 256 + b, pkf(tb32 + (unsigned)e, hb));
  }
  {
    u64 w = spin_pk(henc + (e & 1) * 256, tb32 + (unsigned)e);
    if (sh_abort) return;
    if (tid < NBLK) sh_h[tid] = upf(w);
    __syncthreads();
  }

  // ===================== BRIDGE: exchange dec-gh(h_enc) =====================
  row3(sh_wd, bd0, bd1, bd2, sh_h);
  ++e;
  {
    unsigned tg = tb32 + (unsigned)e;
    if (tid == 0) {
      u64* d = rec + (size_t)(tg & 1) * 1024 + (size_t)b * 4;
      awr(d + 0, pkf(tg, sh_gh3[0]));
      awr(d + 1, pkf(tg, sh_gh3[1]));
      awr(d + 2, pkf(tg, sh_gh3[2]));
    }
    spin_rec3(tg, gh_lds);
    if (sh_abort) return;
  }

  // ===================== DECODER =====================
  int tok = SOS_TOK;
  float2 gp = make_float2(0.f, 0.f);
  if (use_table) {
    if (tid < 384) gp = *(const float2*)(table + (size_t)SOS_TOK * H3 + 2 * tid);
  } else {
    for (int j = tid; j < H; j += NTHR) sh_e[j] = fmaxf(dec_emb[(size_t)SOS_TOK * H + j], 0.f);
    __syncthreads();
    row3(sh_wi, bi0, bi1, bi2, sh_e);
    ++e;
    unsigned tg = tb32 + (unsigned)e;
    if (tid == 0) {
      u64* d = rec + (size_t)(tg & 1) * 1024 + (size_t)b * 4;
      awr(d + 0, pkf(tg, sh_gh3[0]));
      awr(d + 1, pkf(tg, sh_gh3[1]));
      awr(d + 2, pkf(tg, sh_gh3[2]));
    }
    spin_rec3(tg, sh_gi);
    if (sh_abort) return;
  }

  for (int t = 0; t < TSEQ; ++t) {
    if (use_table) {
      if (tid < 384) { sh_gi[2 * tid] = gp.x; sh_gi[2 * tid + 1] = gp.y; }
    }
    __syncthreads();              // covers sh_gi commit + prev-iter gh_lds gather
    gru_step();                   // h_t (bitwise-identical in all blocks)
    // logits from AGPR-resident w_out
    float acc = 0.f;
    if (wact) {
      const float4* h4 = ((const float4*)sh_h) + hf * 32;
#pragma unroll
      for (int i = 0; i < 32; ++i) {
        float4 hv = h4[i];
        float w0 = agpr_r(wa[4 * i + 0]);
        float w1 = agpr_r(wa[4 * i + 1]);
        float w2 = agpr_r(wa[4 * i + 2]);
        float w3 = agpr_r(wa[4 * i + 3]);
        acc += w0 * hv.x + w1 * hv.y + w2 * hv.z + w3 * hv.w;
      }
    }
    acc += __shfl_xor(acc, 1);
    if (wact && hf == 0) sh_logit[p] = acc + sh_bout[p];
    __syncthreads();
    // gh rows for t+1 (depends only on sh_h) -> publish rec EARLY
    row3(sh_wd, bd0, bd1, bd2, sh_h);
    ++e;
    const unsigned tg32 = tb32 + (unsigned)e;
    const unsigned tg16 = (tb16 + (unsigned)e) & 0xFFFFu;
    // block-local max/argmax
    float mv = (tid < nrows) ? sh_logit[tid] : -INFINITY;
    int mi = (tid < nrows) ? (rowbase + tid) : 0x7fffffff;
    wave_maxidx(mv, mi);
    if ((tid & 63) == 0) { sh_mv[tid >> 6] = mv; sh_mi[tid >> 6] = mi; }
    __syncthreads();
    float bmax = sh_mv[0]; int bidx = sh_mi[0];
#pragma unroll
    for (int k = 1; k < 8; ++k)
      if (sh_mv[k] > bmax || (sh_mv[k] == bmax && sh_mi[k] < bidx)) { bmax = sh_mv[k]; bidx = sh_mi[k]; }
    // block-local sum of exp
    float ec = (tid < nrows) ? __expf(sh_logit[tid] - bmax) : 0.f;
#pragma unroll
    for (int off = 32; off >= 1; off >>= 1) ec += __shfl_xor(ec, off);
    if ((tid & 63) == 0) sh_sv[tid >> 6] = ec;
    __syncthreads();
    float bsum = 0.f;
#pragma unroll
    for (int k = 0; k < 8; ++k) bsum += sh_sv[k];
    if (tid == 0) {
      u64* d = rec + (size_t)(e & 1) * 1024 + (size_t)b * 4;
      awr(d + 0, pkf(tg32, sh_gh3[0]));
      awr(d + 1, pkf(tg32, sh_gh3[1]));
      awr(d + 2, pkf(tg32, sh_gh3[2]));
      awr(d + 3, pkf(tg32, bsum));
      // gate word LAST: {tag16, bmax bits, local r}
      u64 g = ((u64)tg16 << 48) | ((u64)__float_as_uint(bmax) << 16) |
              (u64)((unsigned)(bidx - rowbase) & 0xFFFFu);
      awr(pmx + (size_t)(e & 1) * 256 + b, g);
    }
    // spin on packed gate words
    float bm_e = -INFINITY; int ie = 0x7fffffff;
    {
      u64 w = 0;
      if (tid < NBLK) {
        u64* pp_ = pmx + (size_t)(e & 1) * 256 + tid;
        int n = 0;
        do { w = ard(pp_); } while ((unsigned)(w >> 48) != tg16 && ++n < SPIN_LIM);
        if ((unsigned)(w >> 48) != tg16) sh_abort = 1;
        bm_e = __uint_as_float((unsigned)((w >> 16) & 0xFFFFFFFFu));
        ie = tid * RPB + (int)(w & 0xFFFFu);
      }
      __syncthreads();
      if (sh_abort) return;
    }
    // merge argmax -> tok
    float mv2 = bm_e; int mi2 = ie;
    wave_maxidx(mv2, mi2);
    if ((tid & 63) == 0) { sh_mv2[tid >> 6] = mv2; sh_mi2[tid >> 6] = mi2; }
    __syncthreads();
    float gmax = sh_mv2[0]; int gidx = sh_mi2[0];
#pragma unroll
    for (int k = 1; k < 8; ++k)
      if (sh_mv2[k] > gmax || (sh_mv2[k] == gmax && sh_mi2[k] < gidx)) { gmax = sh_mv2[k]; gidx = sh_mi2[k]; }
    tok = gidx;
    // issue next token's gi loads immediately (hide LLC/HBM latency under lse merge)
    if (use_table && t + 1 < TSEQ) {
      if (tid < 384) gp = *(const float2*)(table + (size_t)tok * H3 + 2 * tid);
    }
    // gather rec (gh + bsum), published early -> usually valid on first read
    float sv = 0.f;
    if (tid < NBLK) {
      u64* pp_ = rec + (size_t)(e & 1) * 1024 + (size_t)tid * 4;
      u64 w0 = 0, w1 = 0, w2 = 0, w3 = 0; int n = 0; bool ok;
      do {
        w0 = ard(pp_ + 0); w1 = ard(pp_ + 1); w2 = ard(pp_ + 2); w3 = ard(pp_ + 3);
        ok = (tagof(w0) == tg32) & (tagof(w1) == tg32) & (tagof(w2) == tg32) &
             (tagof(w3) == tg32);
      } while (!ok && ++n < SPIN_LIM);
      if (!ok) sh_abort = 1;
      gh_lds[3 * tid] = upf(w0); gh_lds[3 * tid + 1] = upf(w1); gh_lds[3 * tid + 2] = upf(w2);
      sv = upf(w3);
    }
    __syncthreads();
    if (sh_abort) return;
    // lse merge + output row
    float c = (tid < NBLK) ? sv * __expf(bm_e - gmax) : 0.f;
#pragma unroll
    for (int off = 32; off >= 1; off >>= 1) c += __shfl_xor(c, off);
    if ((tid & 63) == 0) sh_sv2[tid >> 6] = c;
    __syncthreads();
    float S = 0.f;
#pragma unroll
    for (int k = 0; k < 8; ++k) S += sh_sv2[k];
    float lse = gmax + logf(S);
    if (tid < nrows) out[(size_t)t * NV + rowbase + tid] = sh_logit[tid] - lse;
    // !use_table: full gi exchange for next token
    if (!use_table && t + 1 < TSEQ) {
      for (int j = tid; j < H; j += NTHR) sh_e[j] = fmaxf(dec_emb[(size_t)tok * H + j], 0.f);
      __syncthreads();
      row3(sh_wi, bi0, bi1, bi2, sh_e);
      ++e;
      unsigned tgg = tb32 + (unsigned)e;
      if (tid == 0) {
        u64* d = rec + (size_t)(tgg & 1) * 1024 + (size_t)b * 4;
        awr(d + 0, pkf(tgg, sh_gh3[0]));
        awr(d + 1, pkf(tgg, sh_gh3[1]));
        awr(d + 2, pkf(tgg, sh_gh3[2]));
      }
      spin_rec3(tgg, sh_gi);
      if (sh_abort) return;
    }
  }
}

extern "C" void kernel_launch(void* const* d_in, const int* in_sizes, int n_in,
                              void* d_out, int out_size, void* d_ws, size_t ws_size,
                              hipStream_t stream) {
  (void)in_sizes; (void)n_in; (void)out_size;
  const int* x = (const int*)d_in[0];
  const float* enc_emb = (const float*)d_in[1];
  const float* enc_wih = (const float*)d_in[2];
  const float* enc_whh = (const float*)d_in[3];
  const float* enc_bih = (const float*)d_in[4];
  const float* enc_bhh = (const float*)d_in[5];
  const float* dec_emb = (const float*)d_in[6];
  const float* dec_wih = (const float*)d_in[7];
  const float* dec_whh = (const float*)d_in[8];
  const float* dec_bih = (const float*)d_in[9];
  const float* dec_bhh = (const float*)d_in[10];
  const float* w_out = (const float*)d_in[11];
  const float* b_out = (const float*)d_in[12];
  float* out = (float*)d_out;
  char* ws = (char*)d_ws;

  int use_table = (ws_size >= (size_t)WS_TABLE + TABLE_BYTES) ? 1 : 0;

  k_init<<<1, 64, 0, stream>>>(ws);
  k_enc_gi<<<TSEQ / 16, 256, 0, stream>>>(x, enc_emb, enc_wih, enc_bih, (float*)(ws + WS_GIENC));
  if (use_table)
    k_table<<<NV / 16, 256, 0, stream>>>(dec_emb, dec_wih, dec_bih, (float*)(ws + WS_TABLE));
  k_main<<<NBLK, NTHR, 0, stream>>>(enc_whh, enc_bhh, dec_emb, dec_wih, dec_whh, dec_bih,
                                    dec_bhh, w_out, b_out, out, ws, use_table);
}

// Round 8
// 11694.603 us; speedup vs baseline: 1.1983x; 1.1258x over previous
//
#include <hip/hip_runtime.h>
#include <stdint.h>

#define TSEQ 1024
#define H 256
#define H3 768
#define NV 50000
#define NBLK 256
#define NTHR 512
#define RPB 196            // 256 * 196 = 50176 >= 50000
#define SOS_TOK 2
#define SPIN_LIM (1 << 20)
#define NW 32              // encoder worker blocks
#define EPB 8              // h-elements per worker
#define ERPB 24            // encoder W_hh rows per worker (3*EPB)
#define EPAD 260           // padded LDS row stride (floats) -> 2-way banks only

// ---- workspace layout (bytes) ----
#define WS_SALT   0                          // u32, bumped by k_init every launch
#define WS_DONE   512                        // u64 done flag (own line)
#define WS_HENC   1024                       // u64[2][256] packed encoder h words
#define WS_PMX    8192                       // u64[2][256] packed decoder gate words
#define WS_REC    16384                      // u64[2][256][4] (gh0,gh1,gh2,bsum)
#define WS_GIENC  65536                      // float[1024*768] = 3MB
#define WS_TABLE  (65536 + TSEQ * H3 * 4)
#define TABLE_BYTES ((size_t)NV * H3 * 4)

using u64 = unsigned long long;

// relaxed agent-scope atomics: straight to LLC, no wbl2/inv fences, no ordering needed
__device__ __forceinline__ void awr(u64* p, u64 v) {
  __hip_atomic_store(p, v, __ATOMIC_RELAXED, __HIP_MEMORY_SCOPE_AGENT);
}
__device__ __forceinline__ u64 ard(u64* p) {
  return __hip_atomic_load(p, __ATOMIC_RELAXED, __HIP_MEMORY_SCOPE_AGENT);
}
__device__ __forceinline__ u64 pkf(unsigned tg, float f) {
  return ((u64)tg << 32) | (u64)__float_as_uint(f);
}
__device__ __forceinline__ float upf(u64 w) { return __uint_as_float((unsigned)w); }
__device__ __forceinline__ unsigned tagof(u64 w) { return (unsigned)(w >> 32); }

// explicit AGPR residency for the w_out fragment (compiler cannot remat through these)
__device__ __forceinline__ void agpr_w(float& dst, float v) {
  asm volatile("v_accvgpr_write_b32 %0, %1" : "=a"(dst) : "v"(v));
}
__device__ __forceinline__ float agpr_r(float src) {
  float v;
  asm volatile("v_accvgpr_read_b32 %0, %1" : "=v"(v) : "a"(src));
  return v;
}

// ---- init: bump per-launch salt (graph-replay safe; tags self-invalidate) ----
extern "C" __global__ void k_init(char* ws) {
  if (threadIdx.x == 0) {
    unsigned* s = (unsigned*)(ws + WS_SALT);
    *s = *s + 1u;
  }
}

// ---- encoder input-transform: gi_enc[t][r] = b_ih[r] + w_ih[r,:] @ enc_emb[x[t]] ----
extern "C" __global__ void k_enc_gi(const int* __restrict__ x, const float* __restrict__ emb,
                                    const float* __restrict__ wih, const float* __restrict__ bih,
                                    float* __restrict__ gi) {
  int tid = threadIdx.x;
  int t0 = blockIdx.x * 16;
  __shared__ float4 se4[16][H / 4];
  float* se = (float*)se4;
  for (int idx = tid; idx < 16 * H; idx += 256) {
    int j = idx >> 8, k = idx & 255;
    se[j * H + k] = emb[(size_t)x[t0 + j] * H + k];
  }
  __syncthreads();
  for (int q = 0; q < 3; q++) {
    int r = q * H + tid;
    const float4* w4 = (const float4*)(wih + (size_t)r * H);
    float bb = bih[r];
    float a[16];
#pragma unroll
    for (int j = 0; j < 16; j++) a[j] = bb;
    for (int k = 0; k < H / 4; k++) {
      float4 wv = w4[k];
#pragma unroll
      for (int j = 0; j < 16; j++) {
        float4 ev = se4[j][k];
        a[j] += wv.x * ev.x + wv.y * ev.y + wv.z * ev.z + wv.w * ev.w;
      }
    }
#pragma unroll
    for (int j = 0; j < 16; j++) gi[(size_t)(t0 + j) * H3 + r] = a[j];
  }
}

// ---- decoder gi table: table[v][r] = b_ih[r] + w_ih[r,:] @ relu(dec_emb[v]) ----
extern "C" __global__ void k_table(const float* __restrict__ emb, const float* __restrict__ wih,
                                   const float* __restrict__ bih, float* __restrict__ table) {
  int tid = threadIdx.x;
  int v0 = blockIdx.x * 16;
  __shared__ float4 se4[16][H / 4];
  float* se = (float*)se4;
  for (int idx = tid; idx < 16 * H; idx += 256) {
    int j = idx >> 8, k = idx & 255;
    se[j * H + k] = fmaxf(emb[(size_t)(v0 + j) * H + k], 0.f);
  }
  __syncthreads();
  for (int q = 0; q < 3; q++) {
    int r = q * H + tid;
    const float4* w4 = (const float4*)(wih + (size_t)r * H);
    float bb = bih[r];
    float a[16];
#pragma unroll
    for (int j = 0; j < 16; j++) a[j] = bb;
    for (int k = 0; k < H / 4; k++) {
      float4 wv = w4[k];
#pragma unroll
      for (int j = 0; j < 16; j++) {
        float4 ev = se4[j][k];
        a[j] += wv.x * ev.x + wv.y * ev.y + wv.z * ev.z + wv.w * ev.w;
      }
    }
#pragma unroll
    for (int j = 0; j < 16; j++) table[(size_t)(v0 + j) * H3 + r] = a[j];
  }
}

// ---- persistent kernel: 32-block encoder, 256-block decoder ----
extern "C" __global__ void __launch_bounds__(NTHR, 1)
k_main(const float* __restrict__ enc_whh, const float* __restrict__ enc_bhh,
       const float* __restrict__ dec_emb, const float* __restrict__ dec_wih,
       const float* __restrict__ dec_whh, const float* __restrict__ dec_bih,
       const float* __restrict__ dec_bhh, const float* __restrict__ w_out,
       const float* __restrict__ b_out, float* __restrict__ out,
       char* __restrict__ ws, int use_table) {
  const int b = blockIdx.x, tid = threadIdx.x;
  u64* henc = (u64*)(ws + WS_HENC);
  u64* pmx = (u64*)(ws + WS_PMX);
  u64* rec = (u64*)(ws + WS_REC);
  u64* dflag = (u64*)(ws + WS_DONE);
  const float* gi_enc = (const float*)(ws + WS_GIENC);
  const float* table = (const float*)(ws + WS_TABLE);

  __shared__ float sh_wenc[ERPB * EPAD];   // encoder W_hh slice (workers only), ~25KB
  __shared__ float sh_h[H];
  __shared__ float sh_wd[3][H];
  __shared__ float sh_wi[3][H];
  __shared__ float sh_gi[H3];
  __shared__ float gh_lds[H3];
  __shared__ float sh_lg[2][RPB];          // double-buffered logits
  __shared__ float sh_bout[RPB];
  __shared__ float sh_ghE[ERPB];
  __shared__ float sh_gh3[3];
  __shared__ float sh_rv[8];
  __shared__ float sh_mv[8];
  __shared__ int sh_mi[8];
  __shared__ float sh_sv[8];
  __shared__ float sh_mv2[8];
  __shared__ int sh_mi2[8];
  __shared__ float sh_sv2[8];
  __shared__ float sh_e[H];
  __shared__ int sh_abort;

  if (tid == 0) sh_abort = 0;

  // ---- prologue staging ----
  for (int k = tid; k < 3 * H; k += NTHR) {
    int q = k >> 8, c = k & 255;
    sh_wd[q][c] = dec_whh[((size_t)(3 * b + q)) * H + c];
    if (!use_table) sh_wi[q][c] = dec_wih[((size_t)(3 * b + q)) * H + c];
  }
  if (b < NW) {
    for (int k = tid; k < ERPB * H; k += NTHR) {
      int row = k >> 8, c = k & 255;
      int grow = (row / EPB) * H + b * EPB + (row % EPB);  // gate*(H) + element
      sh_wenc[row * EPAD + c] = enc_whh[(size_t)grow * H + c];
    }
  }
  const int eidx = b * EPB + tid;   // worker h-element index (valid for tid<EPB, b<NW)
  float be0 = 0.f, be1 = 0.f, be2 = 0.f;
  if (b < NW && tid < EPB) {
    be0 = enc_bhh[eidx]; be1 = enc_bhh[H + eidx]; be2 = enc_bhh[2 * H + eidx];
  }
  const float bd0 = dec_bhh[3 * b], bd1 = dec_bhh[3 * b + 1], bd2 = dec_bhh[3 * b + 2];
  float bi0 = 0.f, bi1 = 0.f, bi2 = 0.f;
  if (!use_table) { bi0 = dec_bih[3 * b]; bi1 = dec_bih[3 * b + 1]; bi2 = dec_bih[3 * b + 2]; }
  const int rowbase = b * RPB;
  const int nrows = min(RPB, max(0, NV - rowbase));
  const int p = tid >> 1, hf = tid & 1;
  const bool wact = (p < nrows);
  float wa[128];   // w_out fragment in AGPRs
  {
    const float4* wp = (const float4*)(w_out + (size_t)(rowbase + (wact ? p : 0)) * H + hf * 128);
#pragma unroll
    for (int i = 0; i < 32; ++i) {
      float4 v = wact ? wp[i] : make_float4(0.f, 0.f, 0.f, 0.f);
      agpr_w(wa[4 * i + 0], v.x);
      agpr_w(wa[4 * i + 1], v.y);
      agpr_w(wa[4 * i + 2], v.z);
      agpr_w(wa[4 * i + 3], v.w);
    }
  }
  if (tid < RPB) sh_bout[tid] = (tid < nrows) ? b_out[rowbase + tid] : 0.f;
  const unsigned salt = *(volatile unsigned*)(ws + WS_SALT);
  const unsigned tb32 = salt * 65536u;
  const unsigned tb16 = salt * 4096u;
  const unsigned tg_done = tb32 + (unsigned)TSEQ + 1u;
  __syncthreads();

  auto wave_maxidx = [&](float& mv, int& mi) {
#pragma unroll
    for (int off = 32; off >= 1; off >>= 1) {
      float ov = __shfl_xor(mv, off);
      int oi = __shfl_xor(mi, off);
      if (ov > mv || (ov == mv && oi < mi)) { mv = ov; mi = oi; }
    }
  };
  auto row3 = [&](const float(&wr)[3][H], float bb0, float bb1, float bb2, const float* vin) {
    int q = tid >> 7, i = tid & 127;
    float pp = 0.f;
    if (q < 3) pp = wr[q][2 * i] * vin[2 * i] + wr[q][2 * i + 1] * vin[2 * i + 1];
#pragma unroll
    for (int off = 32; off >= 1; off >>= 1) pp += __shfl_xor(pp, off);
    if (q < 3 && (tid & 63) == 0) sh_rv[tid >> 6] = pp;
    __syncthreads();
    if (tid == 0) {
      sh_gh3[0] = sh_rv[0] + sh_rv[1] + bb0;
      sh_gh3[1] = sh_rv[2] + sh_rv[3] + bb1;
      sh_gh3[2] = sh_rv[4] + sh_rv[5] + bb2;
    }
    __syncthreads();
  };
  auto gru_step = [&]() {
    if (tid < H) {
      float gir = sh_gi[tid], giz = sh_gi[H + tid], gin = sh_gi[2 * H + tid];
      float ghr = gh_lds[tid], ghz = gh_lds[H + tid], ghn = gh_lds[2 * H + tid];
      float r = 1.f / (1.f + expf(-(gir + ghr)));
      float z = 1.f / (1.f + expf(-(giz + ghz)));
      float n = tanhf(gin + r * ghn);
      sh_h[tid] = (1.f - z) * n + z * sh_h[tid];
    }
    __syncthreads();
  };
  auto spin_rec3 = [&](unsigned tg, float* dst) {
    if (tid < NBLK) {
      u64* pp_ = rec + (size_t)(tg & 1) * 1024 + (size_t)tid * 4;
      u64 w0 = 0, w1 = 0, w2 = 0; int n = 0; bool ok;
      do {
        w0 = ard(pp_ + 0); w1 = ard(pp_ + 1); w2 = ard(pp_ + 2);
        ok = (tagof(w0) == tg) & (tagof(w1) == tg) & (tagof(w2) == tg);
      } while (!ok && ++n < SPIN_LIM);
      if (!ok) sh_abort = 1;
      dst[3 * tid] = upf(w0); dst[3 * tid + 1] = upf(w1); dst[3 * tid + 2] = upf(w2);
    }
    __syncthreads();
  };

  int e = 0;
  // ===================== ENCODER: 32 worker blocks =====================
  if (b < NW) {
    float hb = 0.f;
    if (tid < EPB) {
      float g0 = gi_enc[eidx], g1 = gi_enc[H + eidx], g2 = gi_enc[2 * H + eidx];
      float r = 1.f / (1.f + expf(-(g0 + be0)));
      float z = 1.f / (1.f + expf(-(g1 + be1)));
      float n = tanhf(g2 + r * be2);
      hb = (1.f - z) * n;
      awr(henc + 256 + eidx, pkf(tb32 + 1u, hb));   // e=1, parity 1
    }
    e = 1;
    for (int t = 1; t < TSEQ; ++t) {
      float g0 = 0.f, g1 = 0.f, g2 = 0.f;
      if (tid < EPB) {
        g0 = gi_enc[(size_t)t * H3 + eidx];
        g1 = gi_enc[(size_t)t * H3 + H + eidx];
        g2 = gi_enc[(size_t)t * H3 + 2 * H + eidx];
      }
      // gather h_t
      if (tid < NBLK) {
        u64* pp_ = henc + (size_t)(e & 1) * 256 + tid;
        u64 w = 0; int n_ = 0;
        do { w = ard(pp_); } while (tagof(w) != tb32 + (unsigned)e && ++n_ < SPIN_LIM);
        if (tagof(w) != tb32 + (unsigned)e) sh_abort = 1;
        sh_h[tid] = upf(w);
      }
      __syncthreads();
      if (sh_abort) return;
      // 24 row-dots, 4 lanes/row
      if (tid < 4 * ERPB) {
        int row = tid >> 2, m = tid & 3;
        const float4* wr4 = (const float4*)(sh_wenc + row * EPAD);
        const float4* h4 = (const float4*)sh_h;
        float pcc = 0.f;
#pragma unroll
        for (int k = 16 * m; k < 16 * m + 16; ++k) {
          float4 wv = wr4[k], hv = h4[k];
          pcc += wv.x * hv.x + wv.y * hv.y + wv.z * hv.z + wv.w * hv.w;
        }
        pcc += __shfl_xor(pcc, 1);
        pcc += __shfl_xor(pcc, 2);
        if (m == 0) sh_ghE[row] = pcc;
      }
      __syncthreads();
      ++e;
      if (tid < EPB) {
        float r = 1.f / (1.f + expf(-(g0 + (sh_ghE[tid] + be0))));
        float z = 1.f / (1.f + expf(-(g1 + (sh_ghE[EPB + tid] + be1))));
        float n = tanhf(g2 + r * (sh_ghE[2 * EPB + tid] + be2));
        hb = (1.f - z) * n + z * hb;
        awr(henc + (size_t)(e & 1) * 256 + eidx, pkf(tb32 + (unsigned)e, hb));
      }
    }
    // final gather: h_enc (e = TSEQ, parity 0)
    if (tid < NBLK) {
      u64* pp_ = henc + tid;
      u64 w = 0; int n_ = 0;
      do { w = ard(pp_); } while (tagof(w) != tb32 + (unsigned)TSEQ && ++n_ < SPIN_LIM);
      if (tagof(w) != tb32 + (unsigned)TSEQ) sh_abort = 1;
      sh_h[tid] = upf(w);
    }
    __syncthreads();
    if (sh_abort) return;
    if (b == 0 && tid == 0) awr(dflag, pkf(tg_done, 0.f));
  } else {
    // waiters: sleep-poll the done flag (1 line), then gather h_enc once
    if (tid == 0) {
      u64 w = 0; int n_ = 0;
      for (;;) {
        w = ard(dflag);
        if (tagof(w) == tg_done) break;
        if (++n_ > SPIN_LIM) { sh_abort = 1; break; }
        __builtin_amdgcn_s_sleep(32);
      }
    }
    __syncthreads();
    if (sh_abort) return;
    if (tid < NBLK) {
      u64* pp_ = henc + tid;
      u64 w = 0; int n_ = 0;
      do { w = ard(pp_); } while (tagof(w) != tb32 + (unsigned)TSEQ && ++n_ < SPIN_LIM);
      if (tagof(w) != tb32 + (unsigned)TSEQ) sh_abort = 1;
      sh_h[tid] = upf(w);
    }
    __syncthreads();
    if (sh_abort) return;
  }
  e = TSEQ;

  // ===================== BRIDGE: exchange dec-gh(h_enc) =====================
  row3(sh_wd, bd0, bd1, bd2, sh_h);
  ++e;
  {
    unsigned tg = tb32 + (unsigned)e;
    if (tid == 0) {
      u64* d = rec + (size_t)(tg & 1) * 1024 + (size_t)b * 4;
      awr(d + 0, pkf(tg, sh_gh3[0]));
      awr(d + 1, pkf(tg, sh_gh3[1]));
      awr(d + 2, pkf(tg, sh_gh3[2]));
    }
    spin_rec3(tg, gh_lds);
    if (sh_abort) return;
  }

  // ===================== DECODER =====================
  int tok = SOS_TOK;
  float2 gp = make_float2(0.f, 0.f);
  if (use_table) {
    if (tid < 384) gp = *(const float2*)(table + (size_t)SOS_TOK * H3 + 2 * tid);
  } else {
    for (int j = tid; j < H; j += NTHR) sh_e[j] = fmaxf(dec_emb[(size_t)SOS_TOK * H + j], 0.f);
    __syncthreads();
    row3(sh_wi, bi0, bi1, bi2, sh_e);
    ++e;
    unsigned tg = tb32 + (unsigned)e;
    if (tid == 0) {
      u64* d = rec + (size_t)(tg & 1) * 1024 + (size_t)b * 4;
      awr(d + 0, pkf(tg, sh_gh3[0]));
      awr(d + 1, pkf(tg, sh_gh3[1]));
      awr(d + 2, pkf(tg, sh_gh3[2]));
    }
    spin_rec3(tg, sh_gi);
    if (sh_abort) return;
  }

  float lse_pend = 0.f;
  for (int t = 0; t < TSEQ; ++t) {
    const int cur = t & 1;
    if (use_table) {
      if (tid < 384) { sh_gi[2 * tid] = gp.x; sh_gi[2 * tid + 1] = gp.y; }
    }
    __syncthreads();
    gru_step();                   // h_t (bitwise-identical in all blocks)
    // logits from AGPR-resident w_out
    float acc = 0.f;
    if (wact) {
      const float4* h4 = ((const float4*)sh_h) + hf * 32;
#pragma unroll
      for (int i = 0; i < 32; ++i) {
        float4 hv = h4[i];
        float w0 = agpr_r(wa[4 * i + 0]);
        float w1 = agpr_r(wa[4 * i + 1]);
        float w2 = agpr_r(wa[4 * i + 2]);
        float w3 = agpr_r(wa[4 * i + 3]);
        acc += w0 * hv.x + w1 * hv.y + w2 * hv.z + w3 * hv.w;
      }
    }
    acc += __shfl_xor(acc, 1);
    if (wact && hf == 0) sh_lg[cur][p] = acc + sh_bout[p];
    __syncthreads();
    // gh rows for t+1
    row3(sh_wd, bd0, bd1, bd2, sh_h);
    ++e;
    const unsigned tg32 = tb32 + (unsigned)e;
    const unsigned tg16 = (tb16 + (unsigned)e) & 0xFFFFu;
    // block-local max/argmax
    float mv = (tid < nrows) ? sh_lg[cur][tid] : -INFINITY;
    int mi = (tid < nrows) ? (rowbase + tid) : 0x7fffffff;
    wave_maxidx(mv, mi);
    if ((tid & 63) == 0) { sh_mv[tid >> 6] = mv; sh_mi[tid >> 6] = mi; }
    __syncthreads();
    float bmax = sh_mv[0]; int bidx = sh_mi[0];
#pragma unroll
    for (int k = 1; k < 8; ++k)
      if (sh_mv[k] > bmax || (sh_mv[k] == bmax && sh_mi[k] < bidx)) { bmax = sh_mv[k]; bidx = sh_mi[k]; }
    // block-local sum of exp
    float ec = (tid < nrows) ? __expf(sh_lg[cur][tid] - bmax) : 0.f;
#pragma unroll
    for (int off = 32; off >= 1; off >>= 1) ec += __shfl_xor(ec, off);
    if ((tid & 63) == 0) sh_sv[tid >> 6] = ec;
    __syncthreads();
    float bsum = 0.f;
#pragma unroll
    for (int k = 0; k < 8; ++k) bsum += sh_sv[k];
    if (tid == 0) {
      u64* d = rec + (size_t)(e & 1) * 1024 + (size_t)b * 4;
      awr(d + 0, pkf(tg32, sh_gh3[0]));
      awr(d + 1, pkf(tg32, sh_gh3[1]));
      awr(d + 2, pkf(tg32, sh_gh3[2]));
      awr(d + 3, pkf(tg32, bsum));
      u64 g = ((u64)tg16 << 48) | ((u64)__float_as_uint(bmax) << 16) |
              (u64)((unsigned)(bidx - rowbase) & 0xFFFFu);
      awr(pmx + (size_t)(e & 1) * 256 + b, g);
    }
    // deferred out-write of row t-1: stores fly while we spin
    if (t > 0 && tid < nrows)
      out[(size_t)(t - 1) * NV + rowbase + tid] = sh_lg[cur ^ 1][tid] - lse_pend;
    // spin on packed gate words
    float bm_e = -INFINITY; int ie = 0x7fffffff;
    {
      u64 w = 0;
      if (tid < NBLK) {
        u64* pp_ = pmx + (size_t)(e & 1) * 256 + tid;
        int n = 0;
        do { w = ard(pp_); } while ((unsigned)(w >> 48) != tg16 && ++n < SPIN_LIM);
        if ((unsigned)(w >> 48) != tg16) sh_abort = 1;
        bm_e = __uint_as_float((unsigned)((w >> 16) & 0xFFFFFFFFu));
        ie = tid * RPB + (int)(w & 0xFFFFu);
      }
      __syncthreads();
      if (sh_abort) return;
    }
    // merge argmax -> tok
    float mv2 = bm_e; int mi2 = ie;
    wave_maxidx(mv2, mi2);
    if ((tid & 63) == 0) { sh_mv2[tid >> 6] = mv2; sh_mi2[tid >> 6] = mi2; }
    __syncthreads();
    float gmax = sh_mv2[0]; int gidx = sh_mi2[0];
#pragma unroll
    for (int k = 1; k < 8; ++k)
      if (sh_mv2[k] > gmax || (sh_mv2[k] == gmax && sh_mi2[k] < gidx)) { gmax = sh_mv2[k]; gidx = sh_mi2[k]; }
    tok = gidx;
    // issue next token's gi table loads immediately
    if (use_table && t + 1 < TSEQ) {
      if (tid < 384) gp = *(const float2*)(table + (size_t)tok * H3 + 2 * tid);
    }
    // gather rec (gh + bsum)
    float sv = 0.f;
    if (tid < NBLK) {
      u64* pp_ = rec + (size_t)(e & 1) * 1024 + (size_t)tid * 4;
      u64 w0 = 0, w1 = 0, w2 = 0, w3 = 0; int n = 0; bool ok;
      do {
        w0 = ard(pp_ + 0); w1 = ard(pp_ + 1); w2 = ard(pp_ + 2); w3 = ard(pp_ + 3);
        ok = (tagof(w0) == tg32) & (tagof(w1) == tg32) & (tagof(w2) == tg32) &
             (tagof(w3) == tg32);
      } while (!ok && ++n < SPIN_LIM);
      if (!ok) sh_abort = 1;
      gh_lds[3 * tid] = upf(w0); gh_lds[3 * tid + 1] = upf(w1); gh_lds[3 * tid + 2] = upf(w2);
      sv = upf(w3);
    }
    __syncthreads();
    if (sh_abort) return;
    // lse merge (result deferred to next iteration's out-write)
    float c = (tid < NBLK) ? sv * __expf(bm_e - gmax) : 0.f;
#pragma unroll
    for (int off = 32; off >= 1; off >>= 1) c += __shfl_xor(c, off);
    if ((tid & 63) == 0) sh_sv2[tid >> 6] = c;
    __syncthreads();
    float S = 0.f;
#pragma unroll
    for (int k = 0; k < 8; ++k) S += sh_sv2[k];
    lse_pend = gmax + logf(S);
    // !use_table: full gi exchange for next token
    if (!use_table && t + 1 < TSEQ) {
      for (int j = tid; j < H; j += NTHR) sh_e[j] = fmaxf(dec_emb[(size_t)tok * H + j], 0.f);
      __syncthreads();
      row3(sh_wi, bi0, bi1, bi2, sh_e);
      ++e;
      unsigned tgg = tb32 + (unsigned)e;
      if (tid == 0) {
        u64* d = rec + (size_t)(tgg & 1) * 1024 + (size_t)b * 4;
        awr(d + 0, pkf(tgg, sh_gh3[0]));
        awr(d + 1, pkf(tgg, sh_gh3[1]));
        awr(d + 2, pkf(tgg, sh_gh3[2]));
      }
      spin_rec3(tgg, sh_gi);
      if (sh_abort) return;
    }
  }
  // flush final output row
  if (tid < nrows)
    out[(size_t)(TSEQ - 1) * NV + rowbase + tid] = sh_lg[(TSEQ - 1) & 1][tid] - lse_pend;
}

extern "C" void kernel_launch(void* const* d_in, const int* in_sizes, int n_in,
                              void* d_out, int out_size, void* d_ws, size_t ws_size,
                              hipStream_t stream) {
  (void)in_sizes; (void)n_in; (void)out_size;
  const int* x = (const int*)d_in[0];
  const float* enc_emb = (const float*)d_in[1];
  const float* enc_wih = (const float*)d_in[2];
  const float* enc_whh = (const float*)d_in[3];
  const float* enc_bih = (const float*)d_in[4];
  const float* enc_bhh = (const float*)d_in[5];
  const float* dec_emb = (const float*)d_in[6];
  const float* dec_wih = (const float*)d_in[7];
  const float* dec_whh = (const float*)d_in[8];
  const float* dec_bih = (const float*)d_in[9];
  const float* dec_bhh = (const float*)d_in[10];
  const float* w_out = (const float*)d_in[11];
  const float* b_out = (const float*)d_in[12];
  float* out = (float*)d_out;
  char* ws = (char*)d_ws;

  int use_table = (ws_size >= (size_t)WS_TABLE + TABLE_BYTES) ? 1 : 0;

  k_init<<<1, 64, 0, stream>>>(ws);
  k_enc_gi<<<TSEQ / 16, 256, 0, stream>>>(x, enc_emb, enc_wih, enc_bih, (float*)(ws + WS_GIENC));
  if (use_table)
    k_table<<<NV / 16, 256, 0, stream>>>(dec_emb, dec_wih, dec_bih, (float*)(ws + WS_TABLE));
  k_main<<<NBLK, NTHR, 0, stream>>>(enc_whh, enc_bhh, dec_emb, dec_wih, dec_whh, dec_bih,
                                    dec_bhh, w_out, b_out, out, ws, use_table);
}

// Round 9
// 9353.938 us; speedup vs baseline: 1.4982x; 1.2502x over previous
//
#include <hip/hip_runtime.h>
#include <stdint.h>

#define TSEQ 1024
#define H 256
#define H3 768
#define NV 50000
#define NBLK 256
#define NTHR 512
#define RPB 196            // 256 * 196 = 50176 >= 50000
#define SOS_TOK 2
#define SPIN_LIM (1 << 20)
#define NEB 4              // encoder blocks
#define EEL 64             // h-elements per encoder block
#define EROWS 192          // W_hh rows per encoder block (3*EEL)

// ---- workspace layout (bytes) ----
#define WS_SALT   0                          // u32, bumped by k_init every launch
#define WS_HENC   1024                       // u64[2][256] packed encoder h words (4KB)
#define WS_PMX    8192                       // u64[2][256] packed decoder gate words (4KB)
#define WS_REC    16384                      // u64[2][256][4] (gh0,gh1,gh2,bsum) (16KB)
#define WS_GIENC  65536                      // float[1024*768] = 3MB
#define WS_TABLE  (65536 + TSEQ * H3 * 4)
#define TABLE_BYTES ((size_t)NV * H3 * 4)

using u64 = unsigned long long;

// relaxed agent-scope atomics: straight to LLC, no wbl2/inv fences, no ordering needed
__device__ __forceinline__ void awr(u64* p, u64 v) {
  __hip_atomic_store(p, v, __ATOMIC_RELAXED, __HIP_MEMORY_SCOPE_AGENT);
}
__device__ __forceinline__ u64 ard(u64* p) {
  return __hip_atomic_load(p, __ATOMIC_RELAXED, __HIP_MEMORY_SCOPE_AGENT);
}
__device__ __forceinline__ u64 pkf(unsigned tg, float f) {
  return ((u64)tg << 32) | (u64)__float_as_uint(f);
}
__device__ __forceinline__ float upf(u64 w) { return __uint_as_float((unsigned)w); }
__device__ __forceinline__ unsigned tagof(u64 w) { return (unsigned)(w >> 32); }

// explicit AGPR residency (compiler cannot remat/reload through these)
__device__ __forceinline__ void agpr_w(float& dst, float v) {
  asm volatile("v_accvgpr_write_b32 %0, %1" : "=a"(dst) : "v"(v));
}
__device__ __forceinline__ float agpr_r(float src) {
  float v;
  asm volatile("v_accvgpr_read_b32 %0, %1" : "=v"(v) : "a"(src));
  return v;
}

// ---- init: bump per-launch salt (graph-replay safe; tags self-invalidate) ----
extern "C" __global__ void k_init(char* ws) {
  if (threadIdx.x == 0) {
    unsigned* s = (unsigned*)(ws + WS_SALT);
    *s = *s + 1u;
  }
}

// ---- encoder input-transform: gi_enc[t][r] = b_ih[r] + w_ih[r,:] @ enc_emb[x[t]] ----
extern "C" __global__ void k_enc_gi(const int* __restrict__ x, const float* __restrict__ emb,
                                    const float* __restrict__ wih, const float* __restrict__ bih,
                                    float* __restrict__ gi) {
  int tid = threadIdx.x;
  int t0 = blockIdx.x * 16;
  __shared__ float4 se4[16][H / 4];
  float* se = (float*)se4;
  for (int idx = tid; idx < 16 * H; idx += 256) {
    int j = idx >> 8, k = idx & 255;
    se[j * H + k] = emb[(size_t)x[t0 + j] * H + k];
  }
  __syncthreads();
  for (int q = 0; q < 3; q++) {
    int r = q * H + tid;
    const float4* w4 = (const float4*)(wih + (size_t)r * H);
    float bb = bih[r];
    float a[16];
#pragma unroll
    for (int j = 0; j < 16; j++) a[j] = bb;
    for (int k = 0; k < H / 4; k++) {
      float4 wv = w4[k];
#pragma unroll
      for (int j = 0; j < 16; j++) {
        float4 ev = se4[j][k];
        a[j] += wv.x * ev.x + wv.y * ev.y + wv.z * ev.z + wv.w * ev.w;
      }
    }
#pragma unroll
    for (int j = 0; j < 16; j++) gi[(size_t)(t0 + j) * H3 + r] = a[j];
  }
}

// ---- decoder gi table: table[v][r] = b_ih[r] + w_ih[r,:] @ relu(dec_emb[v]) ----
extern "C" __global__ void k_table(const float* __restrict__ emb, const float* __restrict__ wih,
                                   const float* __restrict__ bih, float* __restrict__ table) {
  int tid = threadIdx.x;
  int v0 = blockIdx.x * 16;
  __shared__ float4 se4[16][H / 4];
  float* se = (float*)se4;
  for (int idx = tid; idx < 16 * H; idx += 256) {
    int j = idx >> 8, k = idx & 255;
    se[j * H + k] = fmaxf(emb[(size_t)(v0 + j) * H + k], 0.f);
  }
  __syncthreads();
  for (int q = 0; q < 3; q++) {
    int r = q * H + tid;
    const float4* w4 = (const float4*)(wih + (size_t)r * H);
    float bb = bih[r];
    float a[16];
#pragma unroll
    for (int j = 0; j < 16; j++) a[j] = bb;
    for (int k = 0; k < H / 4; k++) {
      float4 wv = w4[k];
#pragma unroll
      for (int j = 0; j < 16; j++) {
        float4 ev = se4[j][k];
        a[j] += wv.x * ev.x + wv.y * ev.y + wv.z * ev.z + wv.w * ev.w;
      }
    }
#pragma unroll
    for (int j = 0; j < 16; j++) table[(size_t)(v0 + j) * H3 + r] = a[j];
  }
}

// ---- encoder: 4 blocks, W_hh slice in AGPRs, one-hop 256-word h exchange ----
extern "C" __global__ void __launch_bounds__(NTHR, 1)
k_enc(const float* __restrict__ enc_whh, const float* __restrict__ enc_bhh,
      char* __restrict__ ws) {
  const int b = blockIdx.x, tid = threadIdx.x;
  u64* henc = (u64*)(ws + WS_HENC);
  const float* gi_enc = (const float*)(ws + WS_GIENC);
  __shared__ float sh_h[H];
  __shared__ float sh_ghE[EROWS];
  __shared__ int sh_abort;
  if (tid == 0) sh_abort = 0;

  // row staging: thread pair (p2, hf) owns half of row rw=p2 (q = rw/64, i = rw%64)
  const int p2 = tid >> 1, hf = tid & 1;
  const bool ract = (p2 < EROWS);
  const int q = p2 >> 6, ri = p2 & 63;
  const size_t grow = ract ? (size_t)(q * H + b * EEL + ri) : 0;
  float wa[128];
  {
    const float4* wp = (const float4*)(enc_whh + grow * H + hf * 128);
#pragma unroll
    for (int k = 0; k < 32; ++k) {
      float4 v = ract ? wp[k] : make_float4(0.f, 0.f, 0.f, 0.f);
      agpr_w(wa[4 * k + 0], v.x);
      agpr_w(wa[4 * k + 1], v.y);
      agpr_w(wa[4 * k + 2], v.z);
      agpr_w(wa[4 * k + 3], v.w);
    }
  }
  const int el = b * EEL + tid;    // owner element (valid tid<EEL)
  float be0 = 0.f, be1 = 0.f, be2 = 0.f;
  if (tid < EEL) { be0 = enc_bhh[el]; be1 = enc_bhh[H + el]; be2 = enc_bhh[2 * H + el]; }
  const unsigned salt = *(volatile unsigned*)(ws + WS_SALT);
  const unsigned tb32 = salt * 65536u;
  __syncthreads();

  float hb = 0.f;
  if (tid < EEL) {   // t=0: gh(h_0=0) = bias
    float g0 = gi_enc[el], g1 = gi_enc[H + el], g2 = gi_enc[2 * H + el];
    float r = 1.f / (1.f + expf(-(g0 + be0)));
    float z = 1.f / (1.f + expf(-(g1 + be1)));
    float n = tanhf(g2 + r * be2);
    hb = (1.f - z) * n;
    awr(henc + 256 + el, pkf(tb32 + 1u, hb));   // ec=1, parity 1
  }
  int ec = 1;
  for (int t = 1; t < TSEQ; ++t) {
    float g0 = 0.f, g1 = 0.f, g2 = 0.f;
    if (tid < EEL) {   // issue gi loads before the spin; latency hides under it
      g0 = gi_enc[(size_t)t * H3 + el];
      g1 = gi_enc[(size_t)t * H3 + H + el];
      g2 = gi_enc[(size_t)t * H3 + 2 * H + el];
    }
    if (tid < H) {     // gather h_t
      u64* pp_ = henc + (size_t)(ec & 1) * 256 + tid;
      u64 w = 0; int n_ = 0;
      do { w = ard(pp_); } while (tagof(w) != tb32 + (unsigned)ec && ++n_ < SPIN_LIM);
      if (tagof(w) != tb32 + (unsigned)ec) sh_abort = 1;
      sh_h[tid] = upf(w);
    }
    __syncthreads();
    if (sh_abort) return;
    // 192 row-dots from AGPR-resident W_hh (2 lanes/row)
    float pcc = 0.f;
    if (ract) {
      const float4* h4 = ((const float4*)sh_h) + hf * 32;
#pragma unroll
      for (int k = 0; k < 32; ++k) {
        float4 hv = h4[k];
        pcc += agpr_r(wa[4 * k + 0]) * hv.x + agpr_r(wa[4 * k + 1]) * hv.y +
               agpr_r(wa[4 * k + 2]) * hv.z + agpr_r(wa[4 * k + 3]) * hv.w;
      }
    }
    pcc += __shfl_xor(pcc, 1);
    if (ract && hf == 0) sh_ghE[p2] = pcc;
    __syncthreads();
    ++ec;
    if (tid < EEL) {
      float r = 1.f / (1.f + expf(-(g0 + (sh_ghE[tid] + be0))));
      float z = 1.f / (1.f + expf(-(g1 + (sh_ghE[EEL + tid] + be1))));
      float n = tanhf(g2 + r * (sh_ghE[2 * EEL + tid] + be2));
      hb = (1.f - z) * n + z * hb;
      awr(henc + (size_t)(ec & 1) * 256 + el, pkf(tb32 + (unsigned)ec, hb));
    }
  }
  // final h_enc sits in henc[parity 0] with tag tb32+TSEQ
}

// ---- decoder: 256 blocks, w_out in AGPRs, one-hop gate+rec exchange ----
extern "C" __global__ void __launch_bounds__(NTHR, 1)
k_dec(const float* __restrict__ dec_emb, const float* __restrict__ dec_wih,
      const float* __restrict__ dec_whh, const float* __restrict__ dec_bih,
      const float* __restrict__ dec_bhh, const float* __restrict__ w_out,
      const float* __restrict__ b_out, float* __restrict__ out,
      char* __restrict__ ws, int use_table) {
  const int b = blockIdx.x, tid = threadIdx.x;
  u64* henc = (u64*)(ws + WS_HENC);
  u64* pmx = (u64*)(ws + WS_PMX);
  u64* rec = (u64*)(ws + WS_REC);
  const float* table = (const float*)(ws + WS_TABLE);

  __shared__ float sh_h[H];
  __shared__ float sh_wd[3][H];
  __shared__ float sh_wi[3][H];
  __shared__ float sh_gi[H3];
  __shared__ float gh_lds[H3];
  __shared__ float sh_lg[2][RPB];
  __shared__ float sh_bout[RPB];
  __shared__ float sh_gh3[3];
  __shared__ float sh_rv[8];
  __shared__ float sh_mv[8];
  __shared__ int sh_mi[8];
  __shared__ float sh_sv[8];
  __shared__ float sh_mv2[8];
  __shared__ int sh_mi2[8];
  __shared__ float sh_sv2[8];
  __shared__ float sh_e[H];
  __shared__ int sh_abort;

  if (tid == 0) sh_abort = 0;

  for (int k = tid; k < 3 * H; k += NTHR) {
    int q = k >> 8, c = k & 255;
    sh_wd[q][c] = dec_whh[((size_t)(3 * b + q)) * H + c];
    if (!use_table) sh_wi[q][c] = dec_wih[((size_t)(3 * b + q)) * H + c];
  }
  const float bd0 = dec_bhh[3 * b], bd1 = dec_bhh[3 * b + 1], bd2 = dec_bhh[3 * b + 2];
  float bi0 = 0.f, bi1 = 0.f, bi2 = 0.f;
  if (!use_table) { bi0 = dec_bih[3 * b]; bi1 = dec_bih[3 * b + 1]; bi2 = dec_bih[3 * b + 2]; }
  const int rowbase = b * RPB;
  const int nrows = min(RPB, max(0, NV - rowbase));
  const int p = tid >> 1, hf = tid & 1;
  const bool wact = (p < nrows);
  float wa[128];   // w_out fragment in AGPRs
  {
    const float4* wp = (const float4*)(w_out + (size_t)(rowbase + (wact ? p : 0)) * H + hf * 128);
#pragma unroll
    for (int i = 0; i < 32; ++i) {
      float4 v = wact ? wp[i] : make_float4(0.f, 0.f, 0.f, 0.f);
      agpr_w(wa[4 * i + 0], v.x);
      agpr_w(wa[4 * i + 1], v.y);
      agpr_w(wa[4 * i + 2], v.z);
      agpr_w(wa[4 * i + 3], v.w);
    }
  }
  if (tid < RPB) sh_bout[tid] = (tid < nrows) ? b_out[rowbase + tid] : 0.f;
  const unsigned salt = *(volatile unsigned*)(ws + WS_SALT);
  const unsigned tb32 = salt * 65536u;
  const unsigned tb24 = salt * 4096u;
  __syncthreads();

  auto wave_maxidx = [&](float& mv, int& mi) {
#pragma unroll
    for (int off = 32; off >= 1; off >>= 1) {
      float ov = __shfl_xor(mv, off);
      int oi = __shfl_xor(mi, off);
      if (ov > mv || (ov == mv && oi < mi)) { mv = ov; mi = oi; }
    }
  };
  auto row3 = [&](const float(&wr)[3][H], float bb0, float bb1, float bb2, const float* vin) {
    int q = tid >> 7, i = tid & 127;
    float pp = 0.f;
    if (q < 3) pp = wr[q][2 * i] * vin[2 * i] + wr[q][2 * i + 1] * vin[2 * i + 1];
#pragma unroll
    for (int off = 32; off >= 1; off >>= 1) pp += __shfl_xor(pp, off);
    if (q < 3 && (tid & 63) == 0) sh_rv[tid >> 6] = pp;
    __syncthreads();
    if (tid == 0) {
      sh_gh3[0] = sh_rv[0] + sh_rv[1] + bb0;
      sh_gh3[1] = sh_rv[2] + sh_rv[3] + bb1;
      sh_gh3[2] = sh_rv[4] + sh_rv[5] + bb2;
    }
    __syncthreads();
  };
  auto gru_step = [&]() {
    if (tid < H) {
      float gir = sh_gi[tid], giz = sh_gi[H + tid], gin = sh_gi[2 * H + tid];
      float ghr = gh_lds[tid], ghz = gh_lds[H + tid], ghn = gh_lds[2 * H + tid];
      float r = 1.f / (1.f + expf(-(gir + ghr)));
      float z = 1.f / (1.f + expf(-(giz + ghz)));
      float n = tanhf(gin + r * ghn);
      sh_h[tid] = (1.f - z) * n + z * sh_h[tid];
    }
    __syncthreads();
  };
  auto spin_rec3 = [&](unsigned tg, float* dst) {
    if (tid < NBLK) {
      u64* pp_ = rec + (size_t)(tg & 1) * 1024 + (size_t)tid * 4;
      u64 w0 = 0, w1 = 0, w2 = 0; int n = 0; bool ok;
      do {
        w0 = ard(pp_ + 0); w1 = ard(pp_ + 1); w2 = ard(pp_ + 2);
        ok = (tagof(w0) == tg) & (tagof(w1) == tg) & (tagof(w2) == tg);
      } while (!ok && ++n < SPIN_LIM);
      if (!ok) sh_abort = 1;
      dst[3 * tid] = upf(w0); dst[3 * tid + 1] = upf(w1); dst[3 * tid + 2] = upf(w2);
    }
    __syncthreads();
  };

  // ---- gather h_enc (published by k_enc at tag tb32+TSEQ, parity 0) ----
  if (tid < NBLK) {
    u64* pp_ = henc + tid;
    u64 w = 0; int n_ = 0;
    do { w = ard(pp_); } while (tagof(w) != tb32 + (unsigned)TSEQ && ++n_ < SPIN_LIM);
    if (tagof(w) != tb32 + (unsigned)TSEQ) sh_abort = 1;
    sh_h[tid] = upf(w);
  }
  __syncthreads();
  if (sh_abort) return;

  int e = TSEQ;
  // ---- bridge: exchange dec-gh(h_enc) ----
  row3(sh_wd, bd0, bd1, bd2, sh_h);
  ++e;
  {
    unsigned tg = tb32 + (unsigned)e;
    if (tid == 0) {
      u64* d = rec + (size_t)(tg & 1) * 1024 + (size_t)b * 4;
      awr(d + 0, pkf(tg, sh_gh3[0]));
      awr(d + 1, pkf(tg, sh_gh3[1]));
      awr(d + 2, pkf(tg, sh_gh3[2]));
    }
    spin_rec3(tg, gh_lds);
    if (sh_abort) return;
  }

  int tok = SOS_TOK;
  float2 gp = make_float2(0.f, 0.f);
  if (use_table) {
    if (tid < 384) gp = *(const float2*)(table + (size_t)SOS_TOK * H3 + 2 * tid);
  } else {
    for (int j = tid; j < H; j += NTHR) sh_e[j] = fmaxf(dec_emb[(size_t)SOS_TOK * H + j], 0.f);
    __syncthreads();
    row3(sh_wi, bi0, bi1, bi2, sh_e);
    ++e;
    unsigned tg = tb32 + (unsigned)e;
    if (tid == 0) {
      u64* d = rec + (size_t)(tg & 1) * 1024 + (size_t)b * 4;
      awr(d + 0, pkf(tg, sh_gh3[0]));
      awr(d + 1, pkf(tg, sh_gh3[1]));
      awr(d + 2, pkf(tg, sh_gh3[2]));
    }
    spin_rec3(tg, sh_gi);
    if (sh_abort) return;
  }

  float lse_pend = 0.f;
  for (int t = 0; t < TSEQ; ++t) {
    const int cur = t & 1;
    if (use_table) {
      if (tid < 384) { sh_gi[2 * tid] = gp.x; sh_gi[2 * tid + 1] = gp.y; }
    }
    __syncthreads();
    gru_step();                   // h_t (bitwise-identical in all blocks)
    // logits from AGPR-resident w_out
    float acc = 0.f;
    if (wact) {
      const float4* h4 = ((const float4*)sh_h) + hf * 32;
#pragma unroll
      for (int i = 0; i < 32; ++i) {
        float4 hv = h4[i];
        acc += agpr_r(wa[4 * i + 0]) * hv.x + agpr_r(wa[4 * i + 1]) * hv.y +
               agpr_r(wa[4 * i + 2]) * hv.z + agpr_r(wa[4 * i + 3]) * hv.w;
      }
    }
    acc += __shfl_xor(acc, 1);
    if (wact && hf == 0) sh_lg[cur][p] = acc + sh_bout[p];
    __syncthreads();
    ++e;
    const unsigned tg32 = tb32 + (unsigned)e;
    const unsigned tg24 = (tb24 + (unsigned)e) & 0xFFFFFFu;
    // block-local max/argmax -> publish gate word IMMEDIATELY (critical path)
    float mv = (tid < nrows) ? sh_lg[cur][tid] : -INFINITY;
    int mi = (tid < nrows) ? (rowbase + tid) : 0x7fffffff;
    wave_maxidx(mv, mi);
    if ((tid & 63) == 0) { sh_mv[tid >> 6] = mv; sh_mi[tid >> 6] = mi; }
    __syncthreads();
    float bmax = sh_mv[0]; int bidx = sh_mi[0];
#pragma unroll
    for (int k = 1; k < 8; ++k)
      if (sh_mv[k] > bmax || (sh_mv[k] == bmax && sh_mi[k] < bidx)) { bmax = sh_mv[k]; bidx = sh_mi[k]; }
    if (tid == 0) {
      u64 g = ((u64)tg24 << 40) | ((u64)__float_as_uint(bmax) << 8) |
              (u64)((unsigned)(bidx - rowbase) & 0xFFu);
      awr(pmx + (size_t)(e & 1) * 256 + b, g);
    }
    // off-critical-path: sum of exp, gh rows for t+1, rec publish
    float ec = (tid < nrows) ? __expf(sh_lg[cur][tid] - bmax) : 0.f;
#pragma unroll
    for (int off = 32; off >= 1; off >>= 1) ec += __shfl_xor(ec, off);
    if ((tid & 63) == 0) sh_sv[tid >> 6] = ec;
    __syncthreads();
    float bsum = 0.f;
#pragma unroll
    for (int k = 0; k < 8; ++k) bsum += sh_sv[k];
    row3(sh_wd, bd0, bd1, bd2, sh_h);
    if (tid == 0) {
      u64* d = rec + (size_t)(e & 1) * 1024 + (size_t)b * 4;
      awr(d + 0, pkf(tg32, sh_gh3[0]));
      awr(d + 1, pkf(tg32, sh_gh3[1]));
      awr(d + 2, pkf(tg32, sh_gh3[2]));
      awr(d + 3, pkf(tg32, bsum));
    }
    // deferred out-write of row t-1: stores fly while we spin
    if (t > 0 && tid < nrows)
      out[(size_t)(t - 1) * NV + rowbase + tid] = sh_lg[cur ^ 1][tid] - lse_pend;
    // spin on packed gate words
    float bm_e = -INFINITY; int ie = 0x7fffffff;
    {
      u64 w = 0;
      if (tid < NBLK) {
        u64* pp_ = pmx + (size_t)(e & 1) * 256 + tid;
        int n = 0;
        do { w = ard(pp_); } while ((unsigned)(w >> 40) != tg24 && ++n < SPIN_LIM);
        if ((unsigned)(w >> 40) != tg24) sh_abort = 1;
        bm_e = __uint_as_float((unsigned)((w >> 8) & 0xFFFFFFFFu));
        ie = tid * RPB + (int)(w & 0xFFu);
      }
      __syncthreads();
      if (sh_abort) return;
    }
    // merge argmax -> tok
    float mv2 = bm_e; int mi2 = ie;
    wave_maxidx(mv2, mi2);
    if ((tid & 63) == 0) { sh_mv2[tid >> 6] = mv2; sh_mi2[tid >> 6] = mi2; }
    __syncthreads();
    float gmax = sh_mv2[0]; int gidx = sh_mi2[0];
#pragma unroll
    for (int k = 1; k < 8; ++k)
      if (sh_mv2[k] > gmax || (sh_mv2[k] == gmax && sh_mi2[k] < gidx)) { gmax = sh_mv2[k]; gidx = sh_mi2[k]; }
    tok = gidx;
    // issue next token's gi table loads immediately
    if (use_table && t + 1 < TSEQ) {
      if (tid < 384) gp = *(const float2*)(table + (size_t)tok * H3 + 2 * tid);
    }
    // gather rec (gh + bsum)
    float sv = 0.f;
    if (tid < NBLK) {
      u64* pp_ = rec + (size_t)(e & 1) * 1024 + (size_t)tid * 4;
      u64 w0 = 0, w1 = 0, w2 = 0, w3 = 0; int n = 0; bool ok;
      do {
        w0 = ard(pp_ + 0); w1 = ard(pp_ + 1); w2 = ard(pp_ + 2); w3 = ard(pp_ + 3);
        ok = (tagof(w0) == tg32) & (tagof(w1) == tg32) & (tagof(w2) == tg32) &
             (tagof(w3) == tg32);
      } while (!ok && ++n < SPIN_LIM);
      if (!ok) sh_abort = 1;
      gh_lds[3 * tid] = upf(w0); gh_lds[3 * tid + 1] = upf(w1); gh_lds[3 * tid + 2] = upf(w2);
      sv = upf(w3);
    }
    __syncthreads();
    if (sh_abort) return;
    // lse merge (write deferred to next iteration)
    float c = (tid < NBLK) ? sv * __expf(bm_e - gmax) : 0.f;
#pragma unroll
    for (int off = 32; off >= 1; off >>= 1) c += __shfl_xor(c, off);
    if ((tid & 63) == 0) sh_sv2[tid >> 6] = c;
    __syncthreads();
    float S = 0.f;
#pragma unroll
    for (int k = 0; k < 8; ++k) S += sh_sv2[k];
    lse_pend = gmax + logf(S);
    // !use_table: full gi exchange for next token
    if (!use_table && t + 1 < TSEQ) {
      for (int j = tid; j < H; j += NTHR) sh_e[j] = fmaxf(dec_emb[(size_t)tok * H + j], 0.f);
      __syncthreads();
      row3(sh_wi, bi0, bi1, bi2, sh_e);
      ++e;
      unsigned tgg = tb32 + (unsigned)e;
      if (tid == 0) {
        u64* d = rec + (size_t)(tgg & 1) * 1024 + (size_t)b * 4;
        awr(d + 0, pkf(tgg, sh_gh3[0]));
        awr(d + 1, pkf(tgg, sh_gh3[1]));
        awr(d + 2, pkf(tgg, sh_gh3[2]));
      }
      spin_rec3(tgg, sh_gi);
      if (sh_abort) return;
    }
  }
  // flush final output row
  if (tid < nrows)
    out[(size_t)(TSEQ - 1) * NV + rowbase + tid] = sh_lg[(TSEQ - 1) & 1][tid] - lse_pend;
}

extern "C" void kernel_launch(void* const* d_in, const int* in_sizes, int n_in,
                              void* d_out, int out_size, void* d_ws, size_t ws_size,
                              hipStream_t stream) {
  (void)in_sizes; (void)n_in; (void)out_size;
  const int* x = (const int*)d_in[0];
  const float* enc_emb = (const float*)d_in[1];
  const float* enc_wih = (const float*)d_in[2];
  const float* enc_whh = (const float*)d_in[3];
  const float* enc_bih = (const float*)d_in[4];
  const float* enc_bhh = (const float*)d_in[5];
  const float* dec_emb = (const float*)d_in[6];
  const float* dec_wih = (const float*)d_in[7];
  const float* dec_whh = (const float*)d_in[8];
  const float* dec_bih = (const float*)d_in[9];
  const float* dec_bhh = (const float*)d_in[10];
  const float* w_out = (const float*)d_in[11];
  const float* b_out = (const float*)d_in[12];
  float* out = (float*)d_out;
  char* ws = (char*)d_ws;

  int use_table = (ws_size >= (size_t)WS_TABLE + TABLE_BYTES) ? 1 : 0;

  k_init<<<1, 64, 0, stream>>>(ws);
  k_enc_gi<<<TSEQ / 16, 256, 0, stream>>>(x, enc_emb, enc_wih, enc_bih, (float*)(ws + WS_GIENC));
  if (use_table)
    k_table<<<NV / 16, 256, 0, stream>>>(dec_emb, dec_wih, dec_bih, (float*)(ws + WS_TABLE));
  k_enc<<<NEB, NTHR, 0, stream>>>(enc_whh, enc_bhh, ws);
  k_dec<<<NBLK, NTHR, 0, stream>>>(dec_emb, dec_wih, dec_whh, dec_bih, dec_bhh,
                                   w_out, b_out, out, ws, use_table);
}

// Round 11
// 8643.844 us; speedup vs baseline: 1.6212x; 1.0822x over previous
//
#include <hip/hip_runtime.h>
#include <stdint.h>

#define TSEQ 1024
#define H 256
#define H3 768
#define NV 50000
#define NBLK 256
#define NTHR 512
#define RPB 196            // 256 * 196 = 50176 >= 50000
#define SOS_TOK 2
#define SPIN_LIM (1 << 20)
#define NEB_L 64           // k_enc launched blocks
#define NEW 4              // encoder workers
#define EEL 64             // h-elements per worker
#define EROWS 192          // W_hh rows per worker (3*EEL)

// ---- workspace layout (bytes) ----
#define WS_SALT   0                          // u32, bumped by k_init every launch
#define WS_DISP   64                         // u32 table-work dispenser
#define WS_ROSTER 128                        // u32[8] XCD roster counters, 64B stride
#define WS_VERD   832                        // u64[4] handshake verdicts (LLC)
#define WS_HENC   1024                       // u64[2][256] packed h words (LLC path + final)
#define WS_PMX    8192                       // u64[2][256] packed decoder gate words
#define WS_REC    16384                      // u64[2][256][4] (gh0,gh1,gh2,bsum)
#define WS_EHL2   32768                      // u64[2][256] intra-XCD L2 exchange region
#define WS_GIENC  65536                      // float[1024*768] = 3MB
#define WS_TABLE  (65536 + TSEQ * H3 * 4)
#define TABLE_BYTES ((size_t)NV * H3 * 4)

using u64 = unsigned long long;

// relaxed agent-scope atomics: straight to LLC (sc1), no wbl2/inv fences
__device__ __forceinline__ void awr(u64* p, u64 v) {
  __hip_atomic_store(p, v, __ATOMIC_RELAXED, __HIP_MEMORY_SCOPE_AGENT);
}
__device__ __forceinline__ u64 ard(u64* p) {
  return __hip_atomic_load(p, __ATOMIC_RELAXED, __HIP_MEMORY_SCOPE_AGENT);
}
__device__ __forceinline__ unsigned ard32(unsigned* p) {
  return __hip_atomic_load(p, __ATOMIC_RELAXED, __HIP_MEMORY_SCOPE_AGENT);
}
__device__ __forceinline__ u64 pkf(unsigned tg, float f) {
  return ((u64)tg << 32) | (u64)__float_as_uint(f);
}
__device__ __forceinline__ u64 pku(unsigned tg, unsigned v) {
  return ((u64)tg << 32) | (u64)v;
}
__device__ __forceinline__ float upf(u64 w) { return __uint_as_float((unsigned)w); }
__device__ __forceinline__ unsigned tagof(u64 w) { return (unsigned)(w >> 32); }

// ---- intra-XCD L2 transport ----
// write: plain store (CDNA L1 is write-through -> lands in the writer XCD's L2)
__device__ __forceinline__ void wgst(u64* p, u64 v) {
  __hip_atomic_store(p, v, __ATOMIC_RELAXED, __HIP_MEMORY_SCOPE_WORKGROUP);
}
// read: atomic add(0) with return-old — executes AT the L2 (never L1-cached),
// so a spin re-reads real L2 state every iteration. Inline asm so the compiler
// cannot canonicalize the idempotent RMW into a plain (L1-cached) load.
__device__ __forceinline__ u64 wgld(u64* p) {
  u64 v;
  asm volatile("global_atomic_add_x2 %0, %1, %2, off sc0\n\ts_waitcnt vmcnt(0)"
               : "=v"(v) : "v"(p), "v"(0ull) : "memory");
  return v;
}

// explicit AGPR residency (compiler cannot remat/reload through these)
__device__ __forceinline__ void agpr_w(float& dst, float v) {
  asm volatile("v_accvgpr_write_b32 %0, %1" : "=a"(dst) : "v"(v));
}
__device__ __forceinline__ float agpr_r(float src) {
  float v;
  asm volatile("v_accvgpr_read_b32 %0, %1" : "=v"(v) : "a"(src));
  return v;
}

// ---- init: bump salt, reset roster + dispenser (graph-replay safe) ----
extern "C" __global__ void k_init(char* ws) {
  if (threadIdx.x == 0) {
    unsigned* s = (unsigned*)(ws + WS_SALT);
    *s = *s + 1u;
    *(unsigned*)(ws + WS_DISP) = 0u;
    for (int i = 0; i < 8; ++i) *(unsigned*)(ws + WS_ROSTER + i * 64) = 0u;
  }
}

// ---- encoder input-transform: gi_enc[t][r] = b_ih[r] + w_ih[r,:] @ enc_emb[x[t]] ----
extern "C" __global__ void k_enc_gi(const int* __restrict__ x, const float* __restrict__ emb,
                                    const float* __restrict__ wih, const float* __restrict__ bih,
                                    float* __restrict__ gi) {
  int tid = threadIdx.x;
  int t0 = blockIdx.x * 16;
  __shared__ float4 se4[16][H / 4];
  float* se = (float*)se4;
  for (int idx = tid; idx < 16 * H; idx += 256) {
    int j = idx >> 8, k = idx & 255;
    se[j * H + k] = emb[(size_t)x[t0 + j] * H + k];
  }
  __syncthreads();
  for (int q = 0; q < 3; q++) {
    int r = q * H + tid;
    const float4* w4 = (const float4*)(wih + (size_t)r * H);
    float bb = bih[r];
    float a[16];
#pragma unroll
    for (int j = 0; j < 16; j++) a[j] = bb;
    for (int k = 0; k < H / 4; k++) {
      float4 wv = w4[k];
#pragma unroll
      for (int j = 0; j < 16; j++) {
        float4 ev = se4[j][k];
        a[j] += wv.x * ev.x + wv.y * ev.y + wv.z * ev.z + wv.w * ev.w;
      }
    }
#pragma unroll
    for (int j = 0; j < 16; j++) gi[(size_t)(t0 + j) * H3 + r] = a[j];
  }
}

// ---- k_enc: 4 workers (L2 transport if same-XCD verified, else LLC) + table fold ----
extern "C" __global__ void __launch_bounds__(NTHR, 1)
k_enc(const float* __restrict__ enc_whh, const float* __restrict__ enc_bhh,
      const float* __restrict__ dec_emb, const float* __restrict__ dec_wih,
      const float* __restrict__ dec_bih, char* __restrict__ ws, int use_table) {
  const int b = blockIdx.x, tid = threadIdx.x;
  u64* henc = (u64*)(ws + WS_HENC);
  u64* ehl2 = (u64*)(ws + WS_EHL2);
  u64* verd = (u64*)(ws + WS_VERD);
  const float* gi_enc = (const float*)(ws + WS_GIENC);
  float* table = (float*)(ws + WS_TABLE);

  __shared__ float se[16 * H];       // table-fold staging (16KB)
  __shared__ float sh_h[H];
  __shared__ float sh_ghE[EROWS];
  __shared__ int sh_xcd, sh_rank, sh_chosen, sh_u, sh_abort;
  if (tid == 0) sh_abort = 0;

  const unsigned salt = *(volatile unsigned*)(ws + WS_SALT);
  const unsigned tb32 = salt * 65536u;

  // ---- roster registration + worker selection ----
  if (tid == 0) {
    unsigned x;
    asm volatile("s_getreg_b32 %0, hwreg(HW_REG_XCC_ID)" : "=s"(x));
    int myxcd = (int)(x & 7u);
    unsigned* rost = (unsigned*)(ws + WS_ROSTER);
    int rank = (int)__hip_atomic_fetch_add(rost + myxcd * 16, 1u,
                                           __ATOMIC_RELAXED, __HIP_MEMORY_SCOPE_AGENT);
    long n_ = 0;
    unsigned tot = 0;
    do {
      tot = 0;
      for (int i = 0; i < 8; ++i) tot += ard32(rost + i * 16);
      if (++n_ > 2000000L) break;
      __builtin_amdgcn_s_sleep(1);
    } while (tot < (unsigned)NEB_L);
    int chosen = -1;
    for (int i = 0; i < 8; ++i) {
      unsigned c = ard32(rost + i * 16);
      if (chosen < 0 && c >= (unsigned)NEW) chosen = i;
    }
    sh_xcd = myxcd; sh_rank = rank; sh_chosen = chosen;
  }
  __syncthreads();
  bool isw;
  int role;
  if (sh_chosen >= 0) { isw = (sh_xcd == sh_chosen) && (sh_rank < NEW); role = sh_rank; }
  else { isw = (b < NEW); role = b; }

  if (!isw) {
    // ---- table fold: non-workers grind k_table units via dispenser ----
    if (!use_table) return;
    unsigned* disp = (unsigned*)(ws + WS_DISP);
    for (;;) {
      if (tid == 0)
        sh_u = (int)__hip_atomic_fetch_add(disp, 1u, __ATOMIC_RELAXED,
                                           __HIP_MEMORY_SCOPE_AGENT);
      __syncthreads();
      int u = sh_u;
      if (u >= NV / 16) return;
      int v0 = u * 16;
      for (int idx = tid; idx < 16 * H; idx += NTHR) {
        int j = idx >> 8, k2 = idx & 255;
        se[j * H + k2] = fmaxf(dec_emb[(size_t)(v0 + j) * H + k2], 0.f);
      }
      __syncthreads();
      for (int r = tid; r < H3; r += NTHR) {
        const float4* w4 = (const float4*)(dec_wih + (size_t)r * H);
        float bb = dec_bih[r];
        float a[16];
#pragma unroll
        for (int j = 0; j < 16; j++) a[j] = bb;
        for (int k = 0; k < H / 4; k++) {
          float4 wv = w4[k];
#pragma unroll
          for (int j = 0; j < 16; j++) {
            const float4 ev = ((const float4*)se)[j * (H / 4) + k];
            a[j] += wv.x * ev.x + wv.y * ev.y + wv.z * ev.z + wv.w * ev.w;
          }
        }
#pragma unroll
        for (int j = 0; j < 16; j++)
          table[(size_t)(v0 + j) * H3 + r] = a[j];
      }
      __syncthreads();
    }
  }

  // ---- workers ----
  const int el = role * EEL + (tid & 63);   // used by tid<EEL only (tid==tid&63 there)
  const int elw = role * EEL + tid;         // write index (tid<EEL)

  // ---- handshake: 8 rehearsal epochs of the REAL exchange pattern through ehl2 ----
  int okl = 1;
  for (int k = 0; k < 8 && okl; ++k) {
    unsigned wtg = tb32 + 50001u + (unsigned)k;
    if (tid < EEL) wgst(ehl2 + (size_t)(k & 1) * 256 + elw, pku(wtg, 0u));
    int lim = (k == 0) ? 6000 : 2000;
    int myok = 1;
    if (tid < H) {
      u64* pp_ = ehl2 + (size_t)(k & 1) * 256 + tid;
      u64 w = 0; int n_ = 0;
      do { w = wgld(pp_); } while (tagof(w) != wtg && ++n_ < lim);
      myok = (tagof(w) == wtg);
    }
    okl = __syncthreads_and(myok);
  }
  // verdict exchange via LLC (all workers agree)
  const unsigned tagV = tb32 + 60001u;
  if (tid == 0) awr(verd + role, pku(tagV, okl ? 0u : 1u));
  int fb = 0;
  if (tid < NEW) {
    u64 w = 0; int n_ = 0;
    do { w = ard(verd + tid); } while (tagof(w) != tagV && ++n_ < SPIN_LIM);
    fb = (tagof(w) != tagV) ? 1 : (int)(w & 1u);
  }
  const bool l2m = __syncthreads_and(fb == 0);
  u64* EX = l2m ? ehl2 : henc;

  // ---- stage W_hh slice into AGPRs (rows {q*H + role*64 + ri}) ----
  const int p2 = tid >> 1, hf = tid & 1;
  const bool ract = (p2 < EROWS);
  const int q = p2 >> 6, ri = p2 & 63;
  const size_t grow = ract ? (size_t)(q * H + role * EEL + ri) : 0;
  float wa[128];
  {
    const float4* wp = (const float4*)(enc_whh + grow * H + hf * 128);
#pragma unroll
    for (int k = 0; k < 32; ++k) {
      float4 v = ract ? wp[k] : make_float4(0.f, 0.f, 0.f, 0.f);
      agpr_w(wa[4 * k + 0], v.x);
      agpr_w(wa[4 * k + 1], v.y);
      agpr_w(wa[4 * k + 2], v.z);
      agpr_w(wa[4 * k + 3], v.w);
    }
  }
  float be0 = 0.f, be1 = 0.f, be2 = 0.f;
  if (tid < EEL) { be0 = enc_bhh[el]; be1 = enc_bhh[H + el]; be2 = enc_bhh[2 * H + el]; }
  __syncthreads();

  float hb = 0.f;
  if (tid < EEL) {   // t=0: gh(h_0=0) = bias
    float g0 = gi_enc[el], g1 = gi_enc[H + el], g2 = gi_enc[2 * H + el];
    float r = 1.f / (1.f + expf(-(g0 + be0)));
    float z = 1.f / (1.f + expf(-(g1 + be1)));
    float n = tanhf(g2 + r * be2);
    hb = (1.f - z) * n;
    u64 w = pkf(tb32 + 1u, hb);
    if (l2m) wgst(EX + 256 + elw, w); else awr(EX + 256 + elw, w);
  }
  int ec = 1;
  for (int t = 1; t < TSEQ; ++t) {
    float g0 = 0.f, g1 = 0.f, g2 = 0.f;
    if (tid < EEL) {   // issue gi loads before the spin
      g0 = gi_enc[(size_t)t * H3 + el];
      g1 = gi_enc[(size_t)t * H3 + H + el];
      g2 = gi_enc[(size_t)t * H3 + 2 * H + el];
    }
    if (tid < H) {     // gather h_t via active transport
      u64* pp_ = EX + (size_t)(ec & 1) * 256 + tid;
      u64 w = 0; int n_ = 0;
      if (l2m) { do { w = wgld(pp_); } while (tagof(w) != tb32 + (unsigned)ec && ++n_ < SPIN_LIM); }
      else     { do { w = ard(pp_); }  while (tagof(w) != tb32 + (unsigned)ec && ++n_ < SPIN_LIM); }
      if (tagof(w) != tb32 + (unsigned)ec) sh_abort = 1;
      sh_h[tid] = upf(w);
    }
    __syncthreads();
    if (sh_abort) return;
    // 192 row-dots from AGPR-resident W_hh (2 lanes/row)
    float pcc = 0.f;
    if (ract) {
      const float4* h4 = ((const float4*)sh_h) + hf * 32;
#pragma unroll
      for (int k = 0; k < 32; ++k) {
        float4 hv = h4[k];
        pcc += agpr_r(wa[4 * k + 0]) * hv.x + agpr_r(wa[4 * k + 1]) * hv.y +
               agpr_r(wa[4 * k + 2]) * hv.z + agpr_r(wa[4 * k + 3]) * hv.w;
      }
    }
    pcc += __shfl_xor(pcc, 1);
    if (ract && hf == 0) sh_ghE[p2] = pcc;
    __syncthreads();
    ++ec;
    if (tid < EEL) {
      float r = 1.f / (1.f + expf(-(g0 + (sh_ghE[tid] + be0))));
      float z = 1.f / (1.f + expf(-(g1 + (sh_ghE[EEL + tid] + be1))));
      float n = tanhf(g2 + r * (sh_ghE[2 * EEL + tid] + be2));
      hb = (1.f - z) * n + z * hb;
      u64 w = pkf(tb32 + (unsigned)ec, hb);
      u64* d = EX + (size_t)(ec & 1) * 256 + elw;
      if (l2m) wgst(d, w); else awr(d, w);
    }
  }
  // final h_enc must be LLC-visible for k_dec (LLC mode already wrote henc parity 0)
  if (l2m && tid < EEL) awr(henc + elw, pkf(tb32 + (unsigned)TSEQ, hb));
}

// ---- decoder: 256 blocks, w_out in AGPRs; deferred-lse pipeline ----
extern "C" __global__ void __launch_bounds__(NTHR, 1)
k_dec(const float* __restrict__ dec_emb, const float* __restrict__ dec_wih,
      const float* __restrict__ dec_whh, const float* __restrict__ dec_bih,
      const float* __restrict__ dec_bhh, const float* __restrict__ w_out,
      const float* __restrict__ b_out, float* __restrict__ out,
      char* __restrict__ ws, int use_table) {
  const int b = blockIdx.x, tid = threadIdx.x;
  u64* henc = (u64*)(ws + WS_HENC);
  u64* pmx = (u64*)(ws + WS_PMX);
  u64* rec = (u64*)(ws + WS_REC);
  const float* table = (const float*)(ws + WS_TABLE);

  __shared__ float sh_h[H];
  __shared__ float sh_wd[3][H];
  __shared__ float sh_wi[3][H];
  __shared__ float sh_gi[H3];
  __shared__ float gh_lds[H3];
  __shared__ float sh_lg[2][RPB];
  __shared__ float sh_bout[RPB];
  __shared__ float sh_gh3[3];
  __shared__ float sh_rv[8];
  __shared__ float sh_mv[8];
  __shared__ int sh_mi[8];
  __shared__ float sh_sv[8];
  __shared__ float sh_mv2[8];
  __shared__ int sh_mi2[8];
  __shared__ float sh_sv2[8];
  __shared__ float sh_e[H];
  __shared__ int sh_abort;

  if (tid == 0) sh_abort = 0;

  for (int k = tid; k < 3 * H; k += NTHR) {
    int q = k >> 8, c = k & 255;
    sh_wd[q][c] = dec_whh[((size_t)(3 * b + q)) * H + c];
    if (!use_table) sh_wi[q][c] = dec_wih[((size_t)(3 * b + q)) * H + c];
  }
  const float bd0 = dec_bhh[3 * b], bd1 = dec_bhh[3 * b + 1], bd2 = dec_bhh[3 * b + 2];
  float bi0 = 0.f, bi1 = 0.f, bi2 = 0.f;
  if (!use_table) { bi0 = dec_bih[3 * b]; bi1 = dec_bih[3 * b + 1]; bi2 = dec_bih[3 * b + 2]; }
  const int rowbase = b * RPB;
  const int nrows = min(RPB, max(0, NV - rowbase));
  const int p = tid >> 1, hf = tid & 1;
  const bool wact = (p < nrows);
  float wa[128];
  {
    const float4* wp = (const float4*)(w_out + (size_t)(rowbase + (wact ? p : 0)) * H + hf * 128);
#pragma unroll
    for (int i = 0; i < 32; ++i) {
      float4 v = wact ? wp[i] : make_float4(0.f, 0.f, 0.f, 0.f);
      agpr_w(wa[4 * i + 0], v.x);
      agpr_w(wa[4 * i + 1], v.y);
      agpr_w(wa[4 * i + 2], v.z);
      agpr_w(wa[4 * i + 3], v.w);
    }
  }
  if (tid < RPB) sh_bout[tid] = (tid < nrows) ? b_out[rowbase + tid] : 0.f;
  const unsigned salt = *(volatile unsigned*)(ws + WS_SALT);
  const unsigned tb32 = salt * 65536u;
  const unsigned tb24 = salt * 4096u;
  __syncthreads();

  auto wave_maxidx = [&](float& mv, int& mi) {
#pragma unroll
    for (int off = 32; off >= 1; off >>= 1) {
      float ov = __shfl_xor(mv, off);
      int oi = __shfl_xor(mi, off);
      if (ov > mv || (ov == mv && oi < mi)) { mv = ov; mi = oi; }
    }
  };
  auto row3 = [&](const float(&wr)[3][H], float bb0, float bb1, float bb2, const float* vin) {
    int q = tid >> 7, i = tid & 127;
    float pp = 0.f;
    if (q < 3) pp = wr[q][2 * i] * vin[2 * i] + wr[q][2 * i + 1] * vin[2 * i + 1];
#pragma unroll
    for (int off = 32; off >= 1; off >>= 1) pp += __shfl_xor(pp, off);
    if (q < 3 && (tid & 63) == 0) sh_rv[tid >> 6] = pp;
    __syncthreads();
    if (tid == 0) {
      sh_gh3[0] = sh_rv[0] + sh_rv[1] + bb0;
      sh_gh3[1] = sh_rv[2] + sh_rv[3] + bb1;
      sh_gh3[2] = sh_rv[4] + sh_rv[5] + bb2;
    }
    __syncthreads();
  };
  auto gru_step = [&]() {
    if (tid < H) {
      float gir = sh_gi[tid], giz = sh_gi[H + tid], gin = sh_gi[2 * H + tid];
      float ghr = gh_lds[tid], ghz = gh_lds[H + tid], ghn = gh_lds[2 * H + tid];
      float r = 1.f / (1.f + expf(-(gir + ghr)));
      float z = 1.f / (1.f + expf(-(giz + ghz)));
      float n = tanhf(gin + r * ghn);
      sh_h[tid] = (1.f - z) * n + z * sh_h[tid];
    }
    __syncthreads();
  };
  auto spin_rec3 = [&](unsigned tg, float* dst) {
    if (tid < NBLK) {
      u64* pp_ = rec + (size_t)(tg & 1) * 1024 + (size_t)tid * 4;
      u64 w0 = 0, w1 = 0, w2 = 0; int n = 0; bool ok;
      do {
        w0 = ard(pp_ + 0); w1 = ard(pp_ + 1); w2 = ard(pp_ + 2);
        ok = (tagof(w0) == tg) & (tagof(w1) == tg) & (tagof(w2) == tg);
      } while (!ok && ++n < SPIN_LIM);
      if (!ok) sh_abort = 1;
      dst[3 * tid] = upf(w0); dst[3 * tid + 1] = upf(w1); dst[3 * tid + 2] = upf(w2);
    }
    __syncthreads();
  };

  // ---- gather h_enc ----
  if (tid < NBLK) {
    u64* pp_ = henc + tid;
    u64 w = 0; int n_ = 0;
    do { w = ard(pp_); } while (tagof(w) != tb32 + (unsigned)TSEQ && ++n_ < SPIN_LIM);
    if (tagof(w) != tb32 + (unsigned)TSEQ) sh_abort = 1;
    sh_h[tid] = upf(w);
  }
  __syncthreads();
  if (sh_abort) return;

  int e = TSEQ;
  // ---- bridge ----
  row3(sh_wd, bd0, bd1, bd2, sh_h);
  ++e;
  {
    unsigned tg = tb32 + (unsigned)e;
    if (tid == 0) {
      u64* d = rec + (size_t)(tg & 1) * 1024 + (size_t)b * 4;
      awr(d + 0, pkf(tg, sh_gh3[0]));
      awr(d + 1, pkf(tg, sh_gh3[1]));
      awr(d + 2, pkf(tg, sh_gh3[2]));
    }
    spin_rec3(tg, gh_lds);
    if (sh_abort) return;
  }

  int tok = SOS_TOK;
  float2 gp = make_float2(0.f, 0.f);
  if (use_table) {
    if (tid < 384) gp = *(const float2*)(table + (size_t)SOS_TOK * H3 + 2 * tid);
  } else {
    for (int j = tid; j < H; j += NTHR) sh_e[j] = fmaxf(dec_emb[(size_t)SOS_TOK * H + j], 0.f);
    __syncthreads();
    row3(sh_wi, bi0, bi1, bi2, sh_e);
    ++e;
    unsigned tg = tb32 + (unsigned)e;
    if (tid == 0) {
      u64* d = rec + (size_t)(tg & 1) * 1024 + (size_t)b * 4;
      awr(d + 0, pkf(tg, sh_gh3[0]));
      awr(d + 1, pkf(tg, sh_gh3[1]));
      awr(d + 2, pkf(tg, sh_gh3[2]));
    }
    spin_rec3(tg, sh_gi);
    if (sh_abort) return;
  }

  // deferred-lse state: step t-1's per-lane sv / bmax and merged gmax
  float sv_p = 0.f, bm_p = -INFINITY, gm_p = 0.f;
  for (int t = 0; t < TSEQ; ++t) {
    const int cur = t & 1;
    if (use_table) {
      if (tid < 384) { sh_gi[2 * tid] = gp.x; sh_gi[2 * tid + 1] = gp.y; }
    }
    __syncthreads();
    gru_step();
    float acc = 0.f;
    if (wact) {
      const float4* h4 = ((const float4*)sh_h) + hf * 32;
#pragma unroll
      for (int i = 0; i < 32; ++i) {
        float4 hv = h4[i];
        acc += agpr_r(wa[4 * i + 0]) * hv.x + agpr_r(wa[4 * i + 1]) * hv.y +
               agpr_r(wa[4 * i + 2]) * hv.z + agpr_r(wa[4 * i + 3]) * hv.w;
      }
    }
    acc += __shfl_xor(acc, 1);
    if (wact && hf == 0) sh_lg[cur][p] = acc + sh_bout[p];
    __syncthreads();
    ++e;
    const unsigned tg32 = tb32 + (unsigned)e;
    const unsigned tg24 = (tb24 + (unsigned)e) & 0xFFFFFFu;
    // block-local max/argmax -> publish gate word IMMEDIATELY
    float mv = (tid < nrows) ? sh_lg[cur][tid] : -INFINITY;
    int mi = (tid < nrows) ? (rowbase + tid) : 0x7fffffff;
    wave_maxidx(mv, mi);
    if ((tid & 63) == 0) { sh_mv[tid >> 6] = mv; sh_mi[tid >> 6] = mi; }
    __syncthreads();
    float bmax = sh_mv[0]; int bidx = sh_mi[0];
#pragma unroll
    for (int k = 1; k < 8; ++k)
      if (sh_mv[k] > bmax || (sh_mv[k] == bmax && sh_mi[k] < bidx)) { bmax = sh_mv[k]; bidx = sh_mi[k]; }
    if (tid == 0) {
      u64 g = ((u64)tg24 << 40) | ((u64)__float_as_uint(bmax) << 8) |
              (u64)((unsigned)(bidx - rowbase) & 0xFFu);
      awr(pmx + (size_t)(e & 1) * 256 + b, g);
    }
    // gh rows for t+1: publish right after row3 (visible sooner)
    row3(sh_wd, bd0, bd1, bd2, sh_h);
    if (tid == 0) {
      u64* d = rec + (size_t)(e & 1) * 1024 + (size_t)b * 4;
      awr(d + 0, pkf(tg32, sh_gh3[0]));
      awr(d + 1, pkf(tg32, sh_gh3[1]));
      awr(d + 2, pkf(tg32, sh_gh3[2]));
    }
    // block-local sum of exp -> bsum word
    float ec = (tid < nrows) ? __expf(sh_lg[cur][tid] - bmax) : 0.f;
#pragma unroll
    for (int off = 32; off >= 1; off >>= 1) ec += __shfl_xor(ec, off);
    if ((tid & 63) == 0) sh_sv[tid >> 6] = ec;
    __syncthreads();
    float bsum = 0.f;
#pragma unroll
    for (int k = 0; k < 8; ++k) bsum += sh_sv[k];
    if (tid == 0)
      awr(rec + (size_t)(e & 1) * 1024 + (size_t)b * 4 + 3, pkf(tg32, bsum));
    // ---- deferred: finalize lse(t-1) + write row t-1 (overlaps the publish->detect gap)
    if (t > 0) {
      float c = (tid < NBLK) ? sv_p * __expf(bm_p - gm_p) : 0.f;
#pragma unroll
      for (int off = 32; off >= 1; off >>= 1) c += __shfl_xor(c, off);
      if ((tid & 63) == 0) sh_sv2[tid >> 6] = c;
      __syncthreads();
      float S = 0.f;
#pragma unroll
      for (int k = 0; k < 8; ++k) S += sh_sv2[k];
      float lse = gm_p + logf(S);
      if (tid < nrows)
        out[(size_t)(t - 1) * NV + rowbase + tid] = sh_lg[cur ^ 1][tid] - lse;
    }
    // spin gate
    float bm_e = -INFINITY; int ie = 0x7fffffff;
    {
      u64 w = 0;
      if (tid < NBLK) {
        u64* pp_ = pmx + (size_t)(e & 1) * 256 + tid;
        int n = 0;
        do { w = ard(pp_); } while ((unsigned)(w >> 40) != tg24 && ++n < SPIN_LIM);
        if ((unsigned)(w >> 40) != tg24) sh_abort = 1;
        bm_e = __uint_as_float((unsigned)((w >> 8) & 0xFFFFFFFFu));
        ie = tid * RPB + (int)(w & 0xFFu);
      }
      __syncthreads();
      if (sh_abort) return;
    }
    // merge argmax -> tok
    float mv2 = bm_e; int mi2 = ie;
    wave_maxidx(mv2, mi2);
    if ((tid & 63) == 0) { sh_mv2[tid >> 6] = mv2; sh_mi2[tid >> 6] = mi2; }
    __syncthreads();
    float gmax = sh_mv2[0]; int gidx = sh_mi2[0];
#pragma unroll
    for (int k = 1; k < 8; ++k)
      if (sh_mv2[k] > gmax || (sh_mv2[k] == gmax && sh_mi2[k] < gidx)) { gmax = sh_mv2[k]; gidx = sh_mi2[k]; }
    tok = gidx;
    // issue next token's gi table loads immediately
    if (use_table && t + 1 < TSEQ) {
      if (tid < 384) gp = *(const float2*)(table + (size_t)tok * H3 + 2 * tid);
    }
    // gather rec (gh + bsum)
    float sv = 0.f;
    if (tid < NBLK) {
      u64* pp_ = rec + (size_t)(e & 1) * 1024 + (size_t)tid * 4;
      u64 w0 = 0, w1 = 0, w2 = 0, w3 = 0; int n = 0; bool ok;
      do {
        w0 = ard(pp_ + 0); w1 = ard(pp_ + 1); w2 = ard(pp_ + 2); w3 = ard(pp_ + 3);
        ok = (tagof(w0) == tg32) & (tagof(w1) == tg32) & (tagof(w2) == tg32) &
             (tagof(w3) == tg32);
      } while (!ok && ++n < SPIN_LIM);
      if (!ok) sh_abort = 1;
      gh_lds[3 * tid] = upf(w0); gh_lds[3 * tid + 1] = upf(w1); gh_lds[3 * tid + 2] = upf(w2);
      sv = upf(w3);
    }
    __syncthreads();
    if (sh_abort) return;
    // carry step-t state to the deferred lse in iteration t+1
    sv_p = sv; bm_p = bm_e; gm_p = gmax;
    // !use_table: full gi exchange for next token
    if (!use_table && t + 1 < TSEQ) {
      for (int j = tid; j < H; j += NTHR) sh_e[j] = fmaxf(dec_emb[(size_t)tok * H + j], 0.f);
      __syncthreads();
      row3(sh_wi, bi0, bi1, bi2, sh_e);
      ++e;
      unsigned tgg = tb32 + (unsigned)e;
      if (tid == 0) {
        u64* d = rec + (size_t)(tgg & 1) * 1024 + (size_t)b * 4;
        awr(d + 0, pkf(tgg, sh_gh3[0]));
        awr(d + 1, pkf(tgg, sh_gh3[1]));
        awr(d + 2, pkf(tgg, sh_gh3[2]));
      }
      spin_rec3(tgg, sh_gi);
      if (sh_abort) return;
    }
  }
  // epilogue: lse + write final row
  {
    float c = (tid < NBLK) ? sv_p * __expf(bm_p - gm_p) : 0.f;
#pragma unroll
    for (int off = 32; off >= 1; off >>= 1) c += __shfl_xor(c, off);
    if ((tid & 63) == 0) sh_sv2[tid >> 6] = c;
    __syncthreads();
    float S = 0.f;
#pragma unroll
    for (int k = 0; k < 8; ++k) S += sh_sv2[k];
    float lse = gm_p + logf(S);
    if (tid < nrows)
      out[(size_t)(TSEQ - 1) * NV + rowbase + tid] = sh_lg[(TSEQ - 1) & 1][tid] - lse;
  }
}

extern "C" void kernel_launch(void* const* d_in, const int* in_sizes, int n_in,
                              void* d_out, int out_size, void* d_ws, size_t ws_size,
                              hipStream_t stream) {
  (void)in_sizes; (void)n_in; (void)out_size;
  const int* x = (const int*)d_in[0];
  const float* enc_emb = (const float*)d_in[1];
  const float* enc_wih = (const float*)d_in[2];
  const float* enc_whh = (const float*)d_in[3];
  const float* enc_bih = (const float*)d_in[4];
  const float* enc_bhh = (const float*)d_in[5];
  const float* dec_emb = (const float*)d_in[6];
  const float* dec_wih = (const float*)d_in[7];
  const float* dec_whh = (const float*)d_in[8];
  const float* dec_bih = (const float*)d_in[9];
  const float* dec_bhh = (const float*)d_in[10];
  const float* w_out = (const float*)d_in[11];
  const float* b_out = (const float*)d_in[12];
  float* out = (float*)d_out;
  char* ws = (char*)d_ws;

  int use_table = (ws_size >= (size_t)WS_TABLE + TABLE_BYTES) ? 1 : 0;

  k_init<<<1, 64, 0, stream>>>(ws);
  k_enc_gi<<<TSEQ / 16, 256, 0, stream>>>(x, enc_emb, enc_wih, enc_bih, (float*)(ws + WS_GIENC));
  k_enc<<<NEB_L, NTHR, 0, stream>>>(enc_whh, enc_bhh, dec_emb, dec_wih, dec_bih, ws, use_table);
  k_dec<<<NBLK, NTHR, 0, stream>>>(dec_emb, dec_wih, dec_whh, dec_bih, dec_bhh,
                                   w_out, b_out, out, ws, use_table);
}